// Round 13
// baseline (4451.788 us; speedup 1.0000x reference)
//
#include <hip/hip_runtime.h>
#include <math.h>
#include <cstdint>

// ---------------- constants ----------------
#define CH 191
#define NPIX 65536
#define MCOEF 74287            // total wavelet coeffs per channel
#define CSTRIDE 74288
#define SW32 4                 // fp32 Jacobi sweeps. Lever CLOSED at 4 (R10).
// (fold(a-b), (a+b) mod 191) layout: addr = df*194 + s, df in [0,95], s in [0,191)
#define NSKEW (96 * 194)       // 18624 elements

__device__ const float g_dlo[10] = {
  0.003335725285001549f, -0.012580751999015526f, -0.006241490213011705f,
  0.07757149384006515f, -0.03224486958502952f, -0.24229488706619015f,
  0.13842814590110342f, 0.7243085284385744f, 0.6038292697974729f,
  0.160102397974125f };
__device__ const float g_dhi[10] = {
  -0.160102397974125f, 0.6038292697974729f, -0.7243085284385744f,
  0.13842814590110342f, 0.24229488706619015f, -0.03224486958502952f,
  -0.07757149384006515f, -0.006241490213011705f, 0.012580751999015526f,
  0.003335725285001549f };

struct TArgs { double t2[15]; };

__device__ __forceinline__ int sk(int a, int b) {
  int s = a + b; if (s >= CH) s -= CH;
  int d = a - b; if (d < 0) d = -d;
  int df = (d > 95) ? (CH - d) : d;
  return df * 194 + s;
}

#define BAR_LGKM() asm volatile("s_waitcnt lgkmcnt(0)\n\ts_barrier" ::: "memory")

// ---------------- ddp = X^T X (fp64 accum) ----------------
__global__ __launch_bounds__(256) void k_ddp(const float* __restrict__ x,
                                             double* __restrict__ ddp) {
  __shared__ float as[32][33];
  __shared__ float bs[32][33];
  int i0 = blockIdx.x * 32, j0 = blockIdx.y * 32;
  if (j0 < i0) return;
  int t = threadIdx.x;
  int n0 = blockIdx.z * 4096;
  int tx = t & 15, ty = t >> 4;
  double a00 = 0, a01 = 0, a10 = 0, a11 = 0;
  for (int nb = 0; nb < 4096; nb += 32) {
    for (int e = t; e < 1024; e += 256) {
      int kk = e >> 5, ii = e & 31;
      int n = n0 + nb + kk;
      as[kk][ii] = (i0 + ii < CH) ? x[(size_t)n * CH + i0 + ii] : 0.f;
      bs[kk][ii] = (j0 + ii < CH) ? x[(size_t)n * CH + j0 + ii] : 0.f;
    }
    __syncthreads();
    #pragma unroll 8
    for (int kk = 0; kk < 32; ++kk) {
      double x0 = as[kk][tx], x1 = as[kk][tx + 16];
      double y0 = bs[kk][ty], y1 = bs[kk][ty + 16];
      a00 += x0 * y0; a01 += x0 * y1; a10 += x1 * y0; a11 += x1 * y1;
    }
    __syncthreads();
  }
  int i = i0 + tx, j = j0 + ty;
  if (i < CH) {
    if (j < CH)      atomicAdd(&ddp[i * CH + j], a00);
    if (j + 16 < CH) atomicAdd(&ddp[i * CH + j + 16], a01);
  }
  if (i + 16 < CH) {
    if (j < CH)      atomicAdd(&ddp[(i + 16) * CH + j], a10);
    if (j + 16 < CH) atomicAdd(&ddp[(i + 16) * CH + j + 16], a11);
  }
}

__global__ void k_mirror(double* __restrict__ ddp) {
  int e = blockIdx.x * 256 + threadIdx.x;
  if (e >= CH * CH) return;
  int i = e / CH, j = e % CH;
  if (i > j) ddp[e] = ddp[j * CH + i];
}

__global__ __launch_bounds__(256) void k_rsum(const float* __restrict__ x,
                                              double* __restrict__ rsum) {
  int t = threadIdx.x;
  if (t >= CH) return;
  int row0 = blockIdx.x * 256;
  double a = 0;
  for (int r = 0; r < 256; ++r) a += (double)x[(size_t)(row0 + r) * CH + t];
  atomicAdd(&rsum[t], a);
}

// ---------------- fp32 approximate inverse via symmetric SWEEP ----------------
// R12's VALU diet (kept for single-variable A/B vs R11): pure-FMA inner loop
// with the col-k overwrite hoisted out (overwritten value identical to the old
// per-element select -> bit-identical), two-level tree select for extraction.
__global__ __launch_bounds__(768) void k_gj(const double* __restrict__ ddp,
                                            float* __restrict__ out) {
  __shared__ float fc[192];
  int t = threadIdx.x;
  int i = t % 192;        // row
  int cg = t / 192;       // column group: cols j = cg*48 + m
  int j0 = cg * 48;
  bool act = (i < CH);
  float a[48];
  #pragma unroll
  for (int m = 0; m < 48; ++m) {
    int j = j0 + m;
    a[m] = (act && j < CH) ? (float)(ddp[i * CH + j] + ((i == j) ? 1e-6 : 0.0)) : 0.f;
  }
  if (t < 192) fc[t] = 0.f;
  __syncthreads();
  for (int k = 0; k < CH; ++k) {
    int cgk = k / 48;
    int mk = k - cgk * 48;
    if (cg == cgk && act) {
      float g[12];
      #pragma unroll
      for (int gq = 0; gq < 12; ++gq) {
        float v = a[gq * 4];
        v = (mk == gq * 4 + 1) ? a[gq * 4 + 1] : v;
        v = (mk == gq * 4 + 2) ? a[gq * 4 + 2] : v;
        v = (mk == gq * 4 + 3) ? a[gq * 4 + 3] : v;
        g[gq] = v;
      }
      int mq4 = mk >> 2;
      float v = g[0];
      #pragma unroll
      for (int gq = 1; gq < 12; ++gq) v = (mq4 == gq) ? g[gq] : v;
      fc[i] = v;
    }
    __syncthreads();
    float dinv = 1.0f / fc[k];
    float fci = fc[i];
    bool iskrow = (i == k);
    float s = fci * dinv;
    #pragma unroll
    for (int mq = 0; mq < 12; ++mq) {
      float4 f4 = *(const float4*)&fc[j0 + mq * 4];
      #pragma unroll
      for (int c4 = 0; c4 < 4; ++c4) {
        int m = mq * 4 + c4;
        float fj = (c4 == 0) ? f4.x : (c4 == 1) ? f4.y : (c4 == 2) ? f4.z : f4.w;
        a[m] = iskrow ? (fj * dinv) : (a[m] - s * fj);
      }
    }
    if (cg == cgk) {
      float colv = iskrow ? (-dinv) : s;
      #pragma unroll
      for (int m = 0; m < 48; ++m) a[m] = (m == mk) ? colv : a[m];
    }
    __syncthreads();
  }
  if (act) {
    #pragma unroll
    for (int m = 0; m < 48; ++m) {
      int j = j0 + m;
      if (j < CH) out[i * CH + j] = -a[m];
    }
  }
}

// ---------------- one Newton refinement step: P = X(2I - A X), fp64 -------
__global__ void k_newton1(const double* __restrict__ ddp, const float* __restrict__ X,
                          double* __restrict__ T) {
  int j = blockIdx.x * 16 + threadIdx.x, i = blockIdx.y * 16 + threadIdx.y;
  if (i >= CH || j >= CH) return;
  double acc = 0;
  for (int k = 0; k < CH; ++k) {
    double a = ddp[i * CH + k] + (i == k ? 1e-6 : 0.0);
    acc += a * (double)X[k * CH + j];
  }
  T[i * CH + j] = (i == j ? 2.0 : 0.0) - acc;
}
__global__ void k_newton2(const float* __restrict__ X, const double* __restrict__ T,
                          double* __restrict__ P) {
  int j = blockIdx.x * 16 + threadIdx.x, i = blockIdx.y * 16 + threadIdx.y;
  if (i >= CH || j >= CH) return;
  double acc = 0;
  for (int k = 0; k < CH; ++k) acc += (double)X[i * CH + k] * T[k * CH + j];
  P[i * CH + j] = acc;
}

// ---------------- per-band regression -> omega ----------------
__global__ __launch_bounds__(256) void k_beta(const double* __restrict__ ddp,
                                              const double* __restrict__ P,
                                              const double* __restrict__ rsum,
                                              double* __restrict__ sqrtom,
                                              double* __restrict__ invs) {
  __shared__ double bet[CH];
  __shared__ double red[256];
  int i = blockIdx.x, t = threadIdx.x;
  double pii = P[i * CH + i];
  for (int j = t; j < CH; j += 256) {
    double pjip = P[j * CH + i] / pii;
    double acc = 0;
    for (int k = 0; k < CH; ++k) {
      double ddpa = (k == i) ? 0.0 : ddp[k * CH + i];
      acc += (P[j * CH + k] - pjip * P[i * CH + k]) * ddpa;
    }
    bet[j] = (j == i) ? 0.0 : acc;
  }
  __syncthreads();
  double s1 = 0, s2 = 0;
  for (int j = t; j < CH; j += 256) {
    double gj = ((j == i) ? 1.0 : 0.0) - bet[j];
    s1 += gj * rsum[j];
    double tj = 0;
    for (int k = 0; k < CH; ++k) {
      double gk = ((k == i) ? 1.0 : 0.0) - bet[k];
      tj += ddp[j * CH + k] * gk;
    }
    s2 += gj * tj;
  }
  red[t] = s1; __syncthreads();
  for (int o = 128; o; o >>= 1) { if (t < o) red[t] += red[t + o]; __syncthreads(); }
  double sumw = red[0]; __syncthreads();
  red[t] = s2; __syncthreads();
  for (int o = 128; o; o >>= 1) { if (t < o) red[t] += red[t + o]; __syncthreads(); }
  if (t == 0) {
    double sumsq = red[0];
    double var = (sumsq - sumw * sumw / 65536.0) / 65535.0;
    if (var < 0) var = 0;
    double so = sqrt(var) + 1e-30;
    sqrtom[i] = so;
    invs[i] = 1.0 / so;
  }
}

// ---------------- whitened Gram: (df,s)-layout fp32 + diag + full fp64 -----
__global__ void k_packG(const double* __restrict__ ddp, const double* __restrict__ invs,
                        float* __restrict__ Gsk, float* __restrict__ dgf,
                        double* __restrict__ G64) {
  int e = blockIdx.x * 256 + threadIdx.x;
  if (e >= CH * CH) return;
  int i = e / CH, j = e % CH;
  double v = ddp[e] * invs[i] * invs[j];
  G64[e] = v;
  if (j >= i) Gsk[sk(i, j)] = (float)v;
  if (j == i) dgf[i] = (float)v;
}

// ---------------- stage A: single-block fp32 Jacobi (two-phase, R4 struct) --
__global__ __launch_bounds__(1024) void k_jac32(const float* __restrict__ Gsk,
                                                const float* __restrict__ dg0,
                                                float2* __restrict__ rlogA) {
  extern __shared__ float As[];
  __shared__ float2 csn[96];
  __shared__ float dg[CH];
  int t = threadIdx.x;

  int jS[5], kS[5]; int ntask = 0;
  for (int id = t; id < 4560; id += 1024) {
    int j = 0, off = 0;
    while (off + (95 - j) <= id) { off += 95 - j; ++j; }
    jS[ntask] = j; kS[ntask] = j + 1 + (id - off);
    ++ntask;
  }
  int a00[5], a01[5], a10[5], a11[5], limA[5], limB[5];
  #pragma unroll
  for (int ii = 0; ii < 5; ++ii) {
    if (ii < ntask) {
      int j = jS[ii], k = kS[ii];
      int A = j + k;
      int B = k - j;
      int dfB = (A > 95) ? (CH - A) : A;
      int bA = B * 194;
      int bB = dfB * 194;
      a00[ii] = (bA + A) * 4;
      a11[ii] = (bA + CH - A) * 4;
      a01[ii] = (bB + CH - B) * 4;
      a10[ii] = (bB + B) * 4;
      limA[ii] = (bA + CH) * 4;
      limB[ii] = (bB + CH) * 4;
    } else {
      a00[ii] = a01[ii] = a10[ii] = a11[ii] = 0;
      limA[ii] = limB[ii] = 1 << 30; jS[ii] = 0; kS[ii] = 1;
    }
  }

  for (int e = t; e < NSKEW; e += 1024) As[e] = Gsk[e];
  if (t < CH) dg[t] = dg0[t];
  __syncthreads();

  const char* Asb = (const char*)As;
  for (int sweep = 0; sweep < SW32; ++sweep) {
    for (int r = 0; r < CH; ++r) {
      float m0[5], m1[5], m2[5], m3[5];
      #pragma unroll
      for (int ii = 0; ii < 5; ++ii) {
        if (ii < ntask) {
          m0[ii] = *(const float*)(Asb + a00[ii]);
          m1[ii] = *(const float*)(Asb + a01[ii]);
          if (jS[ii] != 0) {
            m2[ii] = *(const float*)(Asb + a10[ii]);
            m3[ii] = *(const float*)(Asb + a11[ii]);
          }
        }
      }
      if (t >= 1 && t < 96) {
        int p = r + t; if (p >= CH) p -= CH;
        int q = r - t; if (q < 0) q += CH;
        int ipq = sk(p, q);
        float app = dg[p], aqq = dg[q], apq = As[ipq];
        float c = 1.0f, s = 0.0f, piv = apq, dp = app, dq = aqq;
        if (fabsf(apq) > 3e-7f * (fabsf(app) + fabsf(aqq)) + 1e-30f) {
          float tau = (aqq - app) / (2.0f * apq);
          float tt = copysignf(1.0f, tau) / (fabsf(tau) + sqrtf(1.0f + tau * tau));
          c = 1.0f / sqrtf(1.0f + tt * tt); s = tt * c;
          dp = app - tt * apq; dq = aqq + tt * apq; piv = 0.0f;
        }
        dg[p] = dp; dg[q] = dq;
        As[ipq] = piv;
        csn[t] = make_float2(c, s);
        rlogA[((size_t)(sweep * CH + r)) * 95 + (t - 1)] = make_float2(c, s);
      }
      BAR_LGKM();
      #pragma unroll
      for (int ii = 0; ii < 5; ++ii) {
        if (ii < ntask) {
          float2 ck2 = csn[kS[ii]];
          if (jS[ii] == 0) {
            float vp = m0[ii], vq = m1[ii];
            *(float*)((char*)As + a00[ii]) = ck2.x * vp - ck2.y * vq;
            *(float*)((char*)As + a01[ii]) = ck2.y * vp + ck2.x * vq;
          } else {
            float2 cj2 = csn[jS[ii]];
            float n00 = ck2.x * m0[ii] - ck2.y * m1[ii];
            float n01 = ck2.y * m0[ii] + ck2.x * m1[ii];
            float n10 = ck2.x * m2[ii] - ck2.y * m3[ii];
            float n11 = ck2.y * m2[ii] + ck2.x * m3[ii];
            *(float*)((char*)As + a00[ii]) = cj2.x * n00 - cj2.y * n10;
            *(float*)((char*)As + a10[ii]) = cj2.y * n00 + cj2.x * n10;
            *(float*)((char*)As + a01[ii]) = cj2.x * n01 - cj2.y * n11;
            *(float*)((char*)As + a11[ii]) = cj2.y * n01 + cj2.x * n11;
          }
          a00[ii] += 8; if (a00[ii] >= limA[ii]) a00[ii] -= 764;
          a11[ii] += 8; if (a11[ii] >= limA[ii]) a11[ii] -= 764;
          a01[ii] += 8; if (a01[ii] >= limB[ii]) a01[ii] -= 764;
          a10[ii] += 8; if (a10[ii] >= limB[ii]) a10[ii] -= 764;
        }
      }
      BAR_LGKM();
    }
  }
}

// ---------------- replay fp32 rotations -> Q (fp64, raw orientation) ------
__global__ __launch_bounds__(128) void k_replayA(const float2* __restrict__ rlogA,
                                                 double* __restrict__ Q) {
  __shared__ double vr[CH];
  int row = blockIdx.x, t = threadIdx.x;
  const int NR = SW32 * CH;
  for (int j = t; j < CH; j += 128) vr[j] = (j == row) ? 1.0 : 0.0;
  bool act = (t < 95);
  float2 nb[4];
  #pragma unroll
  for (int u = 0; u < 4; ++u)
    nb[u] = (act && u < NR) ? rlogA[(size_t)u * 95 + t] : make_float2(1.f, 0.f);
  BAR_LGKM();
  int r = 0;
  for (int g = 0; g < NR; g += 4) {
    #pragma unroll
    for (int u = 0; u < 4; ++u) {
      float2 cur = nb[u];
      int gn = g + u + 4;
      nb[u] = (act && gn < NR) ? rlogA[(size_t)gn * 95 + t] : make_float2(1.f, 0.f);
      if (act && cur.y != 0.f) {
        int k = t + 1;
        int p = r + k; if (p >= CH) p -= CH;
        int q = r - k; if (q < 0) q += CH;
        double s = (double)cur.y;
        double c = sqrt(fmax(0.0, 1.0 - s * s));
        double vp = vr[p], vq = vr[q];
        vr[p] = c * vp - s * vq;
        vr[q] = s * vp + c * vq;
      }
      if (++r == CH) r = 0;
      BAR_LGKM();
    }
  }
  for (int j = t; j < CH; j += 128) Q[(size_t)row * CH + j] = vr[j];
}

// ---------------- A' = Q^T G Q (fp64, exact repair of fp32 stage) ---------
__global__ void k_gq(const double* __restrict__ G64, const double* __restrict__ Q,
                     double* __restrict__ T) {
  int j = blockIdx.x * 16 + threadIdx.x, i = blockIdx.y * 16 + threadIdx.y;
  if (i >= CH || j >= CH) return;
  double acc = 0;
  for (int k = 0; k < CH; ++k) acc += G64[i * CH + k] * Q[(size_t)k * CH + j];
  T[i * CH + j] = acc;
}
__global__ void k_qtq(const double* __restrict__ Q, const double* __restrict__ T,
                      double* __restrict__ A2sk, double* __restrict__ dg64) {
  int j = blockIdx.x * 16 + threadIdx.x, i = blockIdx.y * 16 + threadIdx.y;
  if (i >= CH || j >= CH || j < i) return;
  double acc = 0;
  for (int k = 0; k < CH; ++k) acc += Q[(size_t)k * CH + i] * T[k * CH + j];
  if (j == i) dg64[i] = acc;
  else A2sk[sk(i, j)] = acc;
}

// ---------------- stage D: fp64 polish Jacobi (exactly 1 sweep) -----------
__global__ __launch_bounds__(1024) void k_jac64(const double* __restrict__ A2sk,
                                                const double* __restrict__ dg0,
                                                double* __restrict__ eig,
                                                double2* __restrict__ rlogB) {
  extern __shared__ double As64[];
  __shared__ double2 csn[96];
  __shared__ double dg[CH];
  int t = threadIdx.x;

  int jS[5], kS[5]; int ntask = 0;
  for (int id = t; id < 4560; id += 1024) {
    int j = 0, off = 0;
    while (off + (95 - j) <= id) { off += 95 - j; ++j; }
    jS[ntask] = j; kS[ntask] = j + 1 + (id - off);
    ++ntask;
  }
  int a00[5], a01[5], a10[5], a11[5], limA[5], limB[5];
  #pragma unroll
  for (int ii = 0; ii < 5; ++ii) {
    if (ii < ntask) {
      int j = jS[ii], k = kS[ii];
      int A = j + k;
      int B = k - j;
      int dfB = (A > 95) ? (CH - A) : A;
      int bA = B * 194;
      int bB = dfB * 194;
      a00[ii] = (bA + A) * 8;
      a11[ii] = (bA + CH - A) * 8;
      a01[ii] = (bB + CH - B) * 8;
      a10[ii] = (bB + B) * 8;
      limA[ii] = (bA + CH) * 8;
      limB[ii] = (bB + CH) * 8;
    } else {
      a00[ii] = a01[ii] = a10[ii] = a11[ii] = 0;
      limA[ii] = limB[ii] = 1 << 30; jS[ii] = 0; kS[ii] = 1;
    }
  }

  for (int e = t; e < NSKEW; e += 1024) As64[e] = A2sk[e];
  if (t < CH) dg[t] = dg0[t];
  __syncthreads();

  const char* Asb = (const char*)As64;
  for (int r = 0; r < CH; ++r) {
    double m0[5], m1[5], m2[5], m3[5];
    #pragma unroll
    for (int ii = 0; ii < 5; ++ii) {
      if (ii < ntask) {
        m0[ii] = *(const double*)(Asb + a00[ii]);
        m1[ii] = *(const double*)(Asb + a01[ii]);
        if (jS[ii] != 0) {
          m2[ii] = *(const double*)(Asb + a10[ii]);
          m3[ii] = *(const double*)(Asb + a11[ii]);
        }
      }
    }
    if (t >= 1 && t < 96) {
      int p = r + t; if (p >= CH) p -= CH;
      int q = r - t; if (q < 0) q += CH;
      int ipq = sk(p, q);
      double app = dg[p], aqq = dg[q], apq = As64[ipq];
      double c = 1.0, s = 0.0, piv = apq, dp = app, dq = aqq;
      if (fabs(apq) > 4e-16 * (fabs(app) + fabs(aqq)) + 1e-300) {
        double tau = (aqq - app) / (2.0 * apq);
        double tt = copysign(1.0, tau) / (fabs(tau) + sqrt(1.0 + tau * tau));
        c = 1.0 / sqrt(1.0 + tt * tt); s = tt * c;
        dp = app - tt * apq; dq = aqq + tt * apq; piv = 0.0;
      }
      dg[p] = dp; dg[q] = dq;
      As64[ipq] = piv;
      csn[t] = make_double2(c, s);
      rlogB[(size_t)r * 95 + (t - 1)] = make_double2(c, s);
    }
    BAR_LGKM();
    #pragma unroll
    for (int ii = 0; ii < 5; ++ii) {
      if (ii < ntask) {
        double2 ck2 = csn[kS[ii]];
        if (jS[ii] == 0) {
          double vp = m0[ii], vq = m1[ii];
          *(double*)((char*)As64 + a00[ii]) = ck2.x * vp - ck2.y * vq;
          *(double*)((char*)As64 + a01[ii]) = ck2.y * vp + ck2.x * vq;
        } else {
          double2 cj2 = csn[jS[ii]];
          double n00 = ck2.x * m0[ii] - ck2.y * m1[ii];
          double n01 = ck2.y * m0[ii] + ck2.x * m1[ii];
          double n10 = ck2.x * m2[ii] - ck2.y * m3[ii];
          double n11 = ck2.y * m2[ii] + ck2.x * m3[ii];
          *(double*)((char*)As64 + a00[ii]) = cj2.x * n00 - cj2.y * n10;
          *(double*)((char*)As64 + a10[ii]) = cj2.y * n00 + cj2.x * n10;
          *(double*)((char*)As64 + a01[ii]) = cj2.x * n01 - cj2.y * n11;
          *(double*)((char*)As64 + a11[ii]) = cj2.y * n01 + cj2.x * n11;
        }
        a00[ii] += 16; if (a00[ii] >= limA[ii]) a00[ii] -= 1528;
        a11[ii] += 16; if (a11[ii] >= limA[ii]) a11[ii] -= 1528;
        a01[ii] += 16; if (a01[ii] >= limB[ii]) a01[ii] -= 1528;
        a10[ii] += 16; if (a10[ii] >= limB[ii]) a10[ii] -= 1528;
      }
    }
    BAR_LGKM();
  }
  for (int i = t; i < CH; i += 1024) eig[i] = dg[i];
}

// ---------------- apply stage-D rotations to Q rows -> V ------------------
__global__ __launch_bounds__(128) void k_replayB(const double2* __restrict__ rlogB,
                                                 const double* __restrict__ Q,
                                                 double* __restrict__ V) {
  __shared__ double vr[CH];
  int row = blockIdx.x, t = threadIdx.x;
  const int NR = CH;
  for (int j = t; j < CH; j += 128) vr[j] = Q[(size_t)row * CH + j];
  double2 nxt = (t < 95) ? rlogB[t] : make_double2(1.0, 0.0);
  BAR_LGKM();
  for (int g = 0; g < NR; ++g) {
    double2 cur = nxt;
    if (t < 95 && g + 1 < NR) nxt = rlogB[(size_t)(g + 1) * 95 + t];
    if (t < 95 && cur.y != 0.0) {
      int k = t + 1;
      int p = g + k; if (p >= CH) p -= CH;
      int q = g - k; if (q < 0) q += CH;
      double vp = vr[p], vq = vr[q];
      vr[p] = cur.x * vp - cur.y * vq;
      vr[q] = cur.y * vp + cur.x * vq;
    }
    BAR_LGKM();
  }
  for (int j = t; j < CH; j += 128) V[(size_t)row * CH + j] = vr[j];
}

// ---------------- sort eigenpairs (desc) + whitened eigvec matrix ---------
__global__ __launch_bounds__(256) void k_sortprep(const double* __restrict__ eig,
                                                  const double* __restrict__ V,
                                                  const double* __restrict__ invs,
                                                  int* __restrict__ perm,
                                                  float* __restrict__ Vw) {
  __shared__ double ev[CH];
  __shared__ int pm[CH];
  int t = threadIdx.x;
  if (t < CH) ev[t] = eig[t];
  __syncthreads();
  if (t < CH) {
    double my = ev[t];
    int rk = 0;
    for (int j = 0; j < CH; ++j) {
      double o = ev[j];
      rk += (o > my || (o == my && j < t)) ? 1 : 0;
    }
    pm[rk] = t;
  }
  __syncthreads();
  if (t < CH) perm[t] = pm[t];
  for (int e = t; e < 192 * 192; e += 256) {
    int k = e / 192, i = e - k * 192;
    float v = 0.f;
    if (k < CH && i < CH) v = (float)(invs[k] * V[(size_t)k * CH + pm[i]]);
    Vw[e] = v;
  }
}

// ---------------- pcT = (Y V)^T : [CH][NPIX] (R11 verbatim) ----------------
__global__ __launch_bounds__(256) void k_pc(const float* __restrict__ x,
                                            const float* __restrict__ Vw,
                                            float* __restrict__ pcT) {
  __shared__ float xs[16][65];
  __shared__ float vs[16][33];
  int n0 = blockIdx.x * 64, i0 = blockIdx.y * 32;
  int t = threadIdx.x;
  int tn = t & 15, ti = t >> 4;
  float acc[4][2] = {};
  for (int k0 = 0; k0 < 192; k0 += 16) {
    {
      int col = t & 15, row = t >> 4;
      #pragma unroll
      for (int rr = 0; rr < 4; ++rr) {
        int nn = row + rr * 16;
        int k = k0 + col;
        xs[col][nn] = (k < CH) ? x[(size_t)(n0 + nn) * CH + k] : 0.f;
      }
    }
    {
      int ii = t & 31, kk = t >> 5;
      vs[kk][ii] = Vw[(k0 + kk) * 192 + i0 + ii];
      vs[kk + 8][ii] = Vw[(k0 + kk + 8) * 192 + i0 + ii];
    }
    __syncthreads();
    #pragma unroll
    for (int kk = 0; kk < 16; ++kk) {
      float b0 = vs[kk][ti], b1 = vs[kk][ti + 16];
      #pragma unroll
      for (int rr = 0; rr < 4; ++rr) {
        float a = xs[kk][tn + rr * 16];
        acc[rr][0] += a * b0;
        acc[rr][1] += a * b1;
      }
    }
    __syncthreads();
  }
  #pragma unroll
  for (int rr = 0; rr < 4; ++rr)
    #pragma unroll
    for (int bb = 0; bb < 2; ++bb) {
      int i = i0 + ti + bb * 16, n = n0 + tn + rr * 16;
      if (i < CH) pcT[(size_t)i * NPIX + n] = acc[rr][bb];
    }
}

// ---------------- DWT row pass (level 1 only) ----------------
__global__ __launch_bounds__(256) void k_row(const float* __restrict__ in,
                                             float* __restrict__ rb,
                                             int h, int w, int wd, int chS) {
  __shared__ float rowv[256];
  int bid = blockIdx.x;
  int c = bid / h, y = bid % h;
  const float* src = in + (size_t)c * chS + (size_t)y * w;
  int t = threadIdx.x;
  if (t < w) rowv[t] = src[t];
  __syncthreads();
  float* dst = rb + (size_t)(c * h + y) * (2 * wd);
  for (int o = t; o < 2 * wd; o += 256) {
    int b = (o >= wd) ? 1 : 0;
    int xp = b ? o - wd : o;
    float acc = 0.f;
    #pragma unroll
    for (int s = 0; s < 10; ++s) {
      int m = 2 * xp + 1 - s;
      if (m < 0) m = -1 - m;
      else if (m >= w) m = 2 * w - 1 - m;
      acc += (b ? g_dhi[s] : g_dlo[s]) * rowv[m];
    }
    dst[o] = acc;
  }
}

// ---------------- DWT column pass (level 1 only) -----------
__global__ __launch_bounds__(256) void k_col(const float* __restrict__ rb,
                                             float* __restrict__ llout,
                                             float* __restrict__ coeff,
                                             int h, int wd, int hd, int chSout,
                                             int offHi, int offLL, int lastlvl) {
  int c = blockIdx.z, yp = blockIdx.y;
  int xq = blockIdx.x * 256 + threadIdx.x;
  if (xq >= 2 * wd) return;
  const float* base = rb + (size_t)c * h * 2 * wd + xq;
  float lo = 0.f, hi = 0.f;
  #pragma unroll
  for (int s = 0; s < 10; ++s) {
    int m = 2 * yp + 1 - s;
    if (m < 0) m = -1 - m;
    else if (m >= h) m = 2 * h - 1 - m;
    float v = base[(size_t)m * 2 * wd];
    lo += g_dlo[s] * v;
    hi += g_dhi[s] * v;
  }
  float* cc = coeff + (size_t)c * CSTRIDE;
  if (xq < wd) {
    llout[(size_t)c * chSout + (size_t)yp * wd + xq] = lo;
    if (lastlvl) cc[offLL + yp * wd + xq] = lo;
    cc[offHi + 0 * hd * wd + yp * wd + xq] = hi;
  } else {
    int xp = xq - wd;
    cc[offHi + 1 * hd * wd + yp * wd + xp] = lo;
    cc[offHi + 2 * hd * wd + yp * wd + xp] = hi;
  }
}

// ---------------- DWT levels 2-5 fused: LDS-resident cascade --------------
#define DWT_SMEM ((17424 + 18480) * 4)
__global__ __launch_bounds__(256) void k_dwt_tail(const float* __restrict__ llin,
                                                  float* __restrict__ coeff) {
  extern __shared__ float smem[];
  float* A = smem;
  float* B = smem + 17424;
  const int hsz[5]   = {132, 70, 39, 24, 16};
  const int offHiC[4] = {52272, 66972, 71535, 73263};
  int c = blockIdx.x, t = threadIdx.x;
  float* cc = coeff + (size_t)c * CSTRIDE;
  for (int e = t; e < 132 * 132; e += 256) A[e] = llin[(size_t)c * 17424 + e];
  BAR_LGKM();
  #pragma unroll
  for (int l = 0; l < 4; ++l) {
    const int h = hsz[l], w = hsz[l], wd = hsz[l + 1], hd = hsz[l + 1];
    const int w2 = 2 * wd;
    for (int e = t; e < h * w2; e += 256) {
      int y = e / w2, o = e - y * w2;
      int b = (o >= wd) ? 1 : 0;
      int xp = b ? o - wd : o;
      float acc = 0.f;
      #pragma unroll
      for (int s = 0; s < 10; ++s) {
        int m = 2 * xp + 1 - s;
        if (m < 0) m = -1 - m;
        else if (m >= w) m = 2 * w - 1 - m;
        acc += (b ? g_dhi[s] : g_dlo[s]) * A[y * w + m];
      }
      B[y * w2 + o] = acc;
    }
    BAR_LGKM();
    for (int e = t; e < hd * w2; e += 256) {
      int yp = e / w2, xq = e - yp * w2;
      float lo = 0.f, hi = 0.f;
      #pragma unroll
      for (int s = 0; s < 10; ++s) {
        int m = 2 * yp + 1 - s;
        if (m < 0) m = -1 - m;
        else if (m >= h) m = 2 * h - 1 - m;
        float v = B[m * w2 + xq];
        lo += g_dlo[s] * v;
        hi += g_dhi[s] * v;
      }
      if (xq < wd) {
        A[yp * wd + xq] = lo;
        if (l == 3) cc[74031 + yp * wd + xq] = lo;
        cc[offHiC[l] + 0 * hd * wd + yp * wd + xq] = hi;
      } else {
        int xp = xq - wd;
        cc[offHiC[l] + 1 * hd * wd + yp * wd + xp] = lo;
        cc[offHiC[l] + 2 * hd * wd + yp * wd + xp] = hi;
      }
    }
    BAR_LGKM();
  }
}

// ---------------- SURE statistics (per-thread accumulate, then reduce) ----
__global__ __launch_bounds__(256) void k_stats(const float* __restrict__ coeff,
                                               double* __restrict__ stats, TArgs ta) {
  int c = blockIdx.y;
  const float* cc = coeff + (size_t)c * CSTRIDE;
  double sm[15], cnt[15], nrm = 0;
  #pragma unroll
  for (int q = 0; q < 15; ++q) { sm[q] = 0; cnt[q] = 0; }
  for (int idx = blockIdx.x * 256 + threadIdx.x; idx < MCOEF; idx += 24 * 256) {
    double v = (double)cc[idx];
    double v2 = v * v;
    nrm += v2;
    #pragma unroll
    for (int q = 0; q < 15; ++q) {
      sm[q] += fmin(v2, ta.t2[q]);
      cnt[q] += (v2 >= ta.t2[q]) ? 1.0 : 0.0;
    }
  }
  __shared__ double wred[4][31];
  int lane = threadIdx.x & 63, wv = threadIdx.x >> 6;
  for (int q = 0; q < 31; ++q) {
    double val = (q < 15) ? sm[q] : ((q < 30) ? cnt[q - 15] : nrm);
    #pragma unroll
    for (int o = 32; o > 0; o >>= 1) val += __shfl_down(val, o);
    if (lane == 0) wred[wv][q] = val;
  }
  __syncthreads();
  if (threadIdx.x < 31) {
    double sum = wred[0][threadIdx.x] + wred[1][threadIdx.x] +
                 wred[2][threadIdx.x] + wred[3][threadIdx.x];
    atomicAdd(&stats[c * 31 + threadIdx.x], sum);
  }
}

// ---------------- SURE scan + rank + masked projection matrix -------------
__global__ __launch_bounds__(256) void k_sure(const double* __restrict__ stats,
                                              const double* __restrict__ sqrtom,
                                              const double* __restrict__ V,
                                              const int* __restrict__ perm,
                                              const int* __restrict__ min_iter_p,
                                              float* __restrict__ Wm,
                                              int* __restrict__ meta) {
  __shared__ double st[CH * 31];
  __shared__ double minsure[CH];
  __shared__ int rankS;
  int t = threadIdx.x;
  for (int e = t; e < CH * 31; e += 256) st[e] = stats[e];
  __syncthreads();
  if (t == 0) {
    double norm2 = 0;
    for (int c = 0; c < CH; ++c) norm2 += st[c * 31 + 30];
    double K = norm2 - (double)MCOEF * (double)CH;
    double cum[15];
    for (int q = 0; q < 15; ++q) cum[q] = 0;
    for (int r = 0; r < CH; ++r) {
      double mn = 1e300;
      for (int q = 0; q < 15; ++q) {
        double sure = st[r * 31 + q] + 2.0 * st[r * 31 + 15 + q] - (double)MCOEF;
        double s = cum[q] + sure + K;
        cum[q] += s;
        if (s < mn) mn = s;
      }
      minsure[r] = mn;
    }
    int mi = *min_iter_p;
    int rank = CH - 1;
    for (int r = 0; r < CH; ++r) {
      double prev = (r == 0) ? minsure[0] : minsure[r - 1];
      bool cond = (r > mi) && !(minsure[r] > 2.0 * prev);
      if (cond) { rank = r; break; }
    }
    rankS = rank;
    meta[1] = rank;
  }
  __syncthreads();
  int rank = rankS;
  for (int e = t; e < 192 * 192; e += 256) {
    int k = e / 192, c = e - k * 192;
    float v = 0.f;
    if (k < rank && c < CH) v = (float)(sqrtom[c] * V[(size_t)c * CH + perm[k]]);
    Wm[e] = v;
  }
}

// ---------------- out = pcT^T * Wm (R11 verbatim) ----------------
__global__ __launch_bounds__(256) void k_out(const float* __restrict__ pcT,
                                             const float* __restrict__ Wm,
                                             float* __restrict__ out) {
  __shared__ float psx[16][65];
  __shared__ float wsx[16][33];
  int n0 = blockIdx.x * 64, c0 = blockIdx.y * 32;
  int t = threadIdx.x;
  int tc = t & 15, tn = t >> 4;
  float acc[4][2] = {};
  for (int k0 = 0; k0 < 192; k0 += 16) {
    {
      int nn = t & 63, kk0 = t >> 6;
      #pragma unroll
      for (int rr = 0; rr < 4; ++rr) {
        int kk = kk0 + rr * 4;
        int k = k0 + kk;
        psx[kk][nn] = (k < CH) ? pcT[(size_t)k * NPIX + n0 + nn] : 0.f;
      }
    }
    {
      int cc = t & 31, kk = t >> 5;
      wsx[kk][cc] = Wm[(k0 + kk) * 192 + c0 + cc];
      wsx[kk + 8][cc] = Wm[(k0 + kk + 8) * 192 + c0 + cc];
    }
    __syncthreads();
    #pragma unroll
    for (int kk = 0; kk < 16; ++kk) {
      float b0 = wsx[kk][tc], b1 = wsx[kk][tc + 16];
      #pragma unroll
      for (int rr = 0; rr < 4; ++rr) {
        float a = psx[kk][tn + rr * 16];
        acc[rr][0] += a * b0;
        acc[rr][1] += a * b1;
      }
    }
    __syncthreads();
  }
  #pragma unroll
  for (int rr = 0; rr < 4; ++rr)
    #pragma unroll
    for (int bb = 0; bb < 2; ++bb) {
      int n = n0 + tn + rr * 16, c = c0 + tc + bb * 16;
      if (c < CH) out[(size_t)n * CH + c] = acc[rr][bb];
    }
}

// ---------------- host ----------------
extern "C" void kernel_launch(void* const* d_in, const int* in_sizes, int n_in,
                              void* d_out, int out_size, void* d_ws, size_t ws_size,
                              hipStream_t stream) {
  const float* x = (const float*)d_in[0];
  const int* p_min_iter = (const int*)d_in[1];
  float* out = (float*)d_out;
  char* ws = (char*)d_ws;

  size_t cur = 0;
  auto A = [&](size_t b) { size_t o = cur; cur += (b + 511) & ~(size_t)511; return o; };
  double* ddp     = (double*)(ws + A((size_t)CH * CH * 8));
  double* ddpi64  = (double*)(ws + A((size_t)CH * CH * 8));
  double* Tm      = (double*)(ws + A((size_t)CH * CH * 8));
  double* V       = (double*)(ws + A((size_t)CH * CH * 8));
  double* G64     = (double*)(ws + A((size_t)CH * CH * 8));
  double* T64     = (double*)(ws + A((size_t)CH * CH * 8));
  double* Q       = (double*)(ws + A((size_t)CH * CH * 8));
  double* A2sk    = (double*)(ws + A((size_t)NSKEW * 8));
  double* dg64    = (double*)(ws + A((size_t)CH * 8));
  double* eig     = (double*)(ws + A((size_t)CH * 8));
  double* rsum    = (double*)(ws + A((size_t)CH * 8));
  double* sqrtom  = (double*)(ws + A((size_t)CH * 8));
  double* invs    = (double*)(ws + A((size_t)CH * 8));
  double* stats   = (double*)(ws + A((size_t)CH * 31 * 8));
  int* perm       = (int*)(ws + A((size_t)CH * 4));
  int* meta       = (int*)(ws + A(64));
  float* ddpi32   = (float*)(ws + A((size_t)CH * CH * 4));
  float* Gsk      = (float*)(ws + A((size_t)NSKEW * 4));
  float* dgf      = (float*)(ws + A((size_t)CH * 4));
  float* Vw       = (float*)(ws + A((size_t)192 * 192 * 4));
  float* Wm       = (float*)(ws + A((size_t)192 * 192 * 4));
  float2* rlogA   = (float2*)(ws + A((size_t)SW32 * CH * 95 * 8));
  double2* rlogB  = (double2*)(ws + A((size_t)CH * 95 * 16));
  float* pcT      = (float*)(ws + A((size_t)CH * NPIX * 4));
  float* rowbuf   = (float*)(ws + A((size_t)CH * 256 * 264 * 4));
  float* llA      = (float*)(ws + A((size_t)CH * 17424 * 4));
  float* coeff    = (float*)(ws + A((size_t)CH * CSTRIDE * 4));
  (void)ws_size; (void)in_sizes; (void)n_in; (void)out_size;

  hipMemsetAsync(ddp, 0, (size_t)CH * CH * 8, stream);
  hipMemsetAsync(rsum, 0, (size_t)CH * 8, stream);
  hipMemsetAsync(stats, 0, (size_t)CH * 31 * 8, stream);

  const int J32_SMEM = NSKEW * 4;                               // 74496
  const int J64_SMEM = NSKEW * 8;                               // 148992

  k_ddp<<<dim3(6, 6, 16), 256, 0, stream>>>(x, ddp);
  k_mirror<<<143, 256, 0, stream>>>(ddp);
  k_rsum<<<256, 256, 0, stream>>>(x, rsum);
  k_gj<<<1, 768, 0, stream>>>(ddp, ddpi32);
  k_newton1<<<dim3(12, 12), dim3(16, 16), 0, stream>>>(ddp, ddpi32, Tm);
  k_newton2<<<dim3(12, 12), dim3(16, 16), 0, stream>>>(ddpi32, Tm, ddpi64);
  k_beta<<<CH, 256, 0, stream>>>(ddp, ddpi64, rsum, sqrtom, invs);
  k_packG<<<143, 256, 0, stream>>>(ddp, invs, Gsk, dgf, G64);
  (void)hipFuncSetAttribute((const void*)k_jac32,
        hipFuncAttributeMaxDynamicSharedMemorySize, J32_SMEM);
  k_jac32<<<1, 1024, J32_SMEM, stream>>>(Gsk, dgf, rlogA);
  k_replayA<<<CH, 128, 0, stream>>>(rlogA, Q);
  k_gq<<<dim3(12, 12), dim3(16, 16), 0, stream>>>(G64, Q, T64);
  k_qtq<<<dim3(12, 12), dim3(16, 16), 0, stream>>>(Q, T64, A2sk, dg64);
  (void)hipFuncSetAttribute((const void*)k_jac64,
        hipFuncAttributeMaxDynamicSharedMemorySize, J64_SMEM);
  k_jac64<<<1, 1024, J64_SMEM, stream>>>(A2sk, dg64, eig, rlogB);
  k_replayB<<<CH, 128, 0, stream>>>(rlogB, Q, V);
  k_sortprep<<<1, 256, 0, stream>>>(eig, V, invs, perm, Vw);
  k_pc<<<dim3(1024, 6), 256, 0, stream>>>(x, Vw, pcT);

  // DWT level 1 (256 -> 132) via row/col, then levels 2-5 fused in LDS
  k_row<<<CH * 256, 256, 0, stream>>>(pcT, rowbuf, 256, 256, 132, NPIX);
  k_col<<<dim3(2, 132, CH), 256, 0, stream>>>(
      rowbuf, llA, coeff, 256, 132, 132, 132 * 132, 0, 74031, 0);
  (void)hipFuncSetAttribute((const void*)k_dwt_tail,
        hipFuncAttributeMaxDynamicSharedMemorySize, DWT_SMEM);
  k_dwt_tail<<<CH, 256, DWT_SMEM, stream>>>(llA, coeff);

  TArgs ta;
  {
    double tmax = sqrt(log((double)MCOEF));
    for (int j = 0; j < 15; ++j) { double tv = tmax * j / 14.0; ta.t2[j] = tv * tv; }
  }
  k_stats<<<dim3(24, CH), 256, 0, stream>>>(coeff, stats, ta);
  k_sure<<<1, 256, 0, stream>>>(stats, sqrtom, V, perm, p_min_iter, Wm, meta);
  k_out<<<dim3(1024, 6), 256, 0, stream>>>(pcT, Wm, out);
}

// Round 14
// 3667.828 us; speedup vs baseline: 1.2137x; 1.2137x over previous
//
#include <hip/hip_runtime.h>
#include <math.h>
#include <cstdint>

// ---------------- constants ----------------
#define CH 191
#define NPIX 65536
#define MCOEF 74287            // total wavelet coeffs per channel
#define CSTRIDE 74288
#define SW32 4                 // fp32 Jacobi sweeps. Lever CLOSED at 4 (R10).
// (fold(a-b), (a+b) mod 191) layout: addr = df*194 + s, df in [0,95], s in [0,191)
#define NSKEW (96 * 194)       // 18624 elements

__device__ const float g_dlo[10] = {
  0.003335725285001549f, -0.012580751999015526f, -0.006241490213011705f,
  0.07757149384006515f, -0.03224486958502952f, -0.24229488706619015f,
  0.13842814590110342f, 0.7243085284385744f, 0.6038292697974729f,
  0.160102397974125f };
__device__ const float g_dhi[10] = {
  -0.160102397974125f, 0.6038292697974729f, -0.7243085284385744f,
  0.13842814590110342f, 0.24229488706619015f, -0.03224486958502952f,
  -0.07757149384006515f, -0.006241490213011705f, 0.012580751999015526f,
  0.003335725285001549f };

struct TArgs { double t2[15]; };

__device__ __forceinline__ int sk(int a, int b) {
  int s = a + b; if (s >= CH) s -= CH;
  int d = a - b; if (d < 0) d = -d;
  int df = (d > 95) ? (CH - d) : d;
  return df * 194 + s;
}

#define BAR_LGKM() asm volatile("s_waitcnt lgkmcnt(0)\n\ts_barrier" ::: "memory")

// ---------------- ddp = X^T X (fp64 accum) ----------------
__global__ __launch_bounds__(256) void k_ddp(const float* __restrict__ x,
                                             double* __restrict__ ddp) {
  __shared__ float as[32][33];
  __shared__ float bs[32][33];
  int i0 = blockIdx.x * 32, j0 = blockIdx.y * 32;
  if (j0 < i0) return;
  int t = threadIdx.x;
  int n0 = blockIdx.z * 4096;
  int tx = t & 15, ty = t >> 4;
  double a00 = 0, a01 = 0, a10 = 0, a11 = 0;
  for (int nb = 0; nb < 4096; nb += 32) {
    for (int e = t; e < 1024; e += 256) {
      int kk = e >> 5, ii = e & 31;
      int n = n0 + nb + kk;
      as[kk][ii] = (i0 + ii < CH) ? x[(size_t)n * CH + i0 + ii] : 0.f;
      bs[kk][ii] = (j0 + ii < CH) ? x[(size_t)n * CH + j0 + ii] : 0.f;
    }
    __syncthreads();
    #pragma unroll 8
    for (int kk = 0; kk < 32; ++kk) {
      double x0 = as[kk][tx], x1 = as[kk][tx + 16];
      double y0 = bs[kk][ty], y1 = bs[kk][ty + 16];
      a00 += x0 * y0; a01 += x0 * y1; a10 += x1 * y0; a11 += x1 * y1;
    }
    __syncthreads();
  }
  int i = i0 + tx, j = j0 + ty;
  if (i < CH) {
    if (j < CH)      atomicAdd(&ddp[i * CH + j], a00);
    if (j + 16 < CH) atomicAdd(&ddp[i * CH + j + 16], a01);
  }
  if (i + 16 < CH) {
    if (j < CH)      atomicAdd(&ddp[(i + 16) * CH + j], a10);
    if (j + 16 < CH) atomicAdd(&ddp[(i + 16) * CH + j + 16], a11);
  }
}

__global__ void k_mirror(double* __restrict__ ddp) {
  int e = blockIdx.x * 256 + threadIdx.x;
  if (e >= CH * CH) return;
  int i = e / CH, j = e % CH;
  if (i > j) ddp[e] = ddp[j * CH + i];
}

__global__ __launch_bounds__(256) void k_rsum(const float* __restrict__ x,
                                              double* __restrict__ rsum) {
  int t = threadIdx.x;
  if (t >= CH) return;
  int row0 = blockIdx.x * 256;
  double a = 0;
  for (int r = 0; r < 256; ++r) a += (double)x[(size_t)(row0 + r) * CH + t];
  atomicAdd(&rsum[t], a);
}

// ---------------- fp32 approximate inverse via symmetric SWEEP ----------------
// FROZEN at R9's version (proven ~380us across R9/R10/R11). R12/R13's "VALU
// diet" variant (tree select + separate overwrite pass) re-triggered the
// register-spill cliff (+780us) -- any added live state spills a[48].
__global__ __launch_bounds__(768) void k_gj(const double* __restrict__ ddp,
                                            float* __restrict__ out) {
  __shared__ float fc[192];
  int t = threadIdx.x;
  int i = t % 192;        // row
  int cg = t / 192;       // column group: cols j = cg*48 + m
  int j0 = cg * 48;
  bool act = (i < CH);
  float a[48];
  #pragma unroll
  for (int m = 0; m < 48; ++m) {
    int j = j0 + m;
    a[m] = (act && j < CH) ? (float)(ddp[i * CH + j] + ((i == j) ? 1e-6 : 0.0)) : 0.f;
  }
  if (t < 192) fc[t] = 0.f;          // fc[191] stays 0 (pad row no-op)
  __syncthreads();
  for (int k = 0; k < CH; ++k) {
    int cgk = k / 48;                // wave-uniform across each cg's 3 waves
    int mk = k - cgk * 48;
    if (cg == cgk && act) {
      float v = 0.f;
      #pragma unroll
      for (int m = 0; m < 48; ++m) v = (m == mk) ? a[m] : v;   // static idx
      fc[i] = v;
    }
    __syncthreads();
    float dinv = 1.0f / fc[k];
    float fci = fc[i];
    bool iskrow = (i == k);
    float s = fci * dinv;
    float colv = iskrow ? (-dinv) : s;   // b_kk = -1/d ; b_ik = a_ik/d
    #pragma unroll
    for (int mq = 0; mq < 12; ++mq) {
      float4 f4 = *(const float4*)&fc[j0 + mq * 4];
      #pragma unroll
      for (int c4 = 0; c4 < 4; ++c4) {
        int m = mq * 4 + c4;
        float fj = (c4 == 0) ? f4.x : (c4 == 1) ? f4.y : (c4 == 2) ? f4.z : f4.w;
        float gen = iskrow ? (fj * dinv) : (a[m] - s * fj);
        bool iskcol = (cg == cgk) && (m == mk);
        a[m] = iskcol ? colv : gen;
      }
    }
    __syncthreads();
  }
  if (act) {
    #pragma unroll
    for (int m = 0; m < 48; ++m) {
      int j = j0 + m;
      if (j < CH) out[i * CH + j] = -a[m];
    }
  }
}

// ---------------- one Newton refinement step: P = X(2I - A X), fp64 -------
__global__ void k_newton1(const double* __restrict__ ddp, const float* __restrict__ X,
                          double* __restrict__ T) {
  int j = blockIdx.x * 16 + threadIdx.x, i = blockIdx.y * 16 + threadIdx.y;
  if (i >= CH || j >= CH) return;
  double acc = 0;
  for (int k = 0; k < CH; ++k) {
    double a = ddp[i * CH + k] + (i == k ? 1e-6 : 0.0);
    acc += a * (double)X[k * CH + j];
  }
  T[i * CH + j] = (i == j ? 2.0 : 0.0) - acc;
}
__global__ void k_newton2(const float* __restrict__ X, const double* __restrict__ T,
                          double* __restrict__ P) {
  int j = blockIdx.x * 16 + threadIdx.x, i = blockIdx.y * 16 + threadIdx.y;
  if (i >= CH || j >= CH) return;
  double acc = 0;
  for (int k = 0; k < CH; ++k) acc += (double)X[i * CH + k] * T[k * CH + j];
  P[i * CH + j] = acc;
}

// ---------------- per-band regression -> omega ----------------
__global__ __launch_bounds__(256) void k_beta(const double* __restrict__ ddp,
                                              const double* __restrict__ P,
                                              const double* __restrict__ rsum,
                                              double* __restrict__ sqrtom,
                                              double* __restrict__ invs) {
  __shared__ double bet[CH];
  __shared__ double red[256];
  int i = blockIdx.x, t = threadIdx.x;
  double pii = P[i * CH + i];
  for (int j = t; j < CH; j += 256) {
    double pjip = P[j * CH + i] / pii;
    double acc = 0;
    for (int k = 0; k < CH; ++k) {
      double ddpa = (k == i) ? 0.0 : ddp[k * CH + i];
      acc += (P[j * CH + k] - pjip * P[i * CH + k]) * ddpa;
    }
    bet[j] = (j == i) ? 0.0 : acc;
  }
  __syncthreads();
  double s1 = 0, s2 = 0;
  for (int j = t; j < CH; j += 256) {
    double gj = ((j == i) ? 1.0 : 0.0) - bet[j];
    s1 += gj * rsum[j];
    double tj = 0;
    for (int k = 0; k < CH; ++k) {
      double gk = ((k == i) ? 1.0 : 0.0) - bet[k];
      tj += ddp[j * CH + k] * gk;
    }
    s2 += gj * tj;
  }
  red[t] = s1; __syncthreads();
  for (int o = 128; o; o >>= 1) { if (t < o) red[t] += red[t + o]; __syncthreads(); }
  double sumw = red[0]; __syncthreads();
  red[t] = s2; __syncthreads();
  for (int o = 128; o; o >>= 1) { if (t < o) red[t] += red[t + o]; __syncthreads(); }
  if (t == 0) {
    double sumsq = red[0];
    double var = (sumsq - sumw * sumw / 65536.0) / 65535.0;
    if (var < 0) var = 0;
    double so = sqrt(var) + 1e-30;
    sqrtom[i] = so;
    invs[i] = 1.0 / so;
  }
}

// ---------------- whitened Gram: (df,s)-layout fp32 + diag + full fp64 -----
__global__ void k_packG(const double* __restrict__ ddp, const double* __restrict__ invs,
                        float* __restrict__ Gsk, float* __restrict__ dgf,
                        double* __restrict__ G64) {
  int e = blockIdx.x * 256 + threadIdx.x;
  if (e >= CH * CH) return;
  int i = e / CH, j = e % CH;
  double v = ddp[e] * invs[i] * invs[j];
  G64[e] = v;
  if (j >= i) Gsk[sk(i, j)] = (float)v;
  if (j == i) dgf[i] = (float)v;
}

// ---------------- stage A: single-block fp32 Jacobi (two-phase, R4 struct) --
__global__ __launch_bounds__(1024) void k_jac32(const float* __restrict__ Gsk,
                                                const float* __restrict__ dg0,
                                                float2* __restrict__ rlogA) {
  extern __shared__ float As[];
  __shared__ float2 csn[96];
  __shared__ float dg[CH];
  int t = threadIdx.x;

  int jS[5], kS[5]; int ntask = 0;
  for (int id = t; id < 4560; id += 1024) {
    int j = 0, off = 0;
    while (off + (95 - j) <= id) { off += 95 - j; ++j; }
    jS[ntask] = j; kS[ntask] = j + 1 + (id - off);
    ++ntask;
  }
  int a00[5], a01[5], a10[5], a11[5], limA[5], limB[5];
  #pragma unroll
  for (int ii = 0; ii < 5; ++ii) {
    if (ii < ntask) {
      int j = jS[ii], k = kS[ii];
      int A = j + k;
      int B = k - j;
      int dfB = (A > 95) ? (CH - A) : A;
      int bA = B * 194;
      int bB = dfB * 194;
      a00[ii] = (bA + A) * 4;
      a11[ii] = (bA + CH - A) * 4;
      a01[ii] = (bB + CH - B) * 4;
      a10[ii] = (bB + B) * 4;
      limA[ii] = (bA + CH) * 4;
      limB[ii] = (bB + CH) * 4;
    } else {
      a00[ii] = a01[ii] = a10[ii] = a11[ii] = 0;
      limA[ii] = limB[ii] = 1 << 30; jS[ii] = 0; kS[ii] = 1;
    }
  }

  for (int e = t; e < NSKEW; e += 1024) As[e] = Gsk[e];
  if (t < CH) dg[t] = dg0[t];
  __syncthreads();

  const char* Asb = (const char*)As;
  for (int sweep = 0; sweep < SW32; ++sweep) {
    for (int r = 0; r < CH; ++r) {
      float m0[5], m1[5], m2[5], m3[5];
      #pragma unroll
      for (int ii = 0; ii < 5; ++ii) {
        if (ii < ntask) {
          m0[ii] = *(const float*)(Asb + a00[ii]);
          m1[ii] = *(const float*)(Asb + a01[ii]);
          if (jS[ii] != 0) {
            m2[ii] = *(const float*)(Asb + a10[ii]);
            m3[ii] = *(const float*)(Asb + a11[ii]);
          }
        }
      }
      if (t >= 1 && t < 96) {
        int p = r + t; if (p >= CH) p -= CH;
        int q = r - t; if (q < 0) q += CH;
        int ipq = sk(p, q);
        float app = dg[p], aqq = dg[q], apq = As[ipq];
        float c = 1.0f, s = 0.0f, piv = apq, dp = app, dq = aqq;
        if (fabsf(apq) > 3e-7f * (fabsf(app) + fabsf(aqq)) + 1e-30f) {
          float tau = (aqq - app) / (2.0f * apq);
          float tt = copysignf(1.0f, tau) / (fabsf(tau) + sqrtf(1.0f + tau * tau));
          c = 1.0f / sqrtf(1.0f + tt * tt); s = tt * c;
          dp = app - tt * apq; dq = aqq + tt * apq; piv = 0.0f;
        }
        dg[p] = dp; dg[q] = dq;
        As[ipq] = piv;
        csn[t] = make_float2(c, s);
        rlogA[((size_t)(sweep * CH + r)) * 95 + (t - 1)] = make_float2(c, s);
      }
      BAR_LGKM();
      #pragma unroll
      for (int ii = 0; ii < 5; ++ii) {
        if (ii < ntask) {
          float2 ck2 = csn[kS[ii]];
          if (jS[ii] == 0) {
            float vp = m0[ii], vq = m1[ii];
            *(float*)((char*)As + a00[ii]) = ck2.x * vp - ck2.y * vq;
            *(float*)((char*)As + a01[ii]) = ck2.y * vp + ck2.x * vq;
          } else {
            float2 cj2 = csn[jS[ii]];
            float n00 = ck2.x * m0[ii] - ck2.y * m1[ii];
            float n01 = ck2.y * m0[ii] + ck2.x * m1[ii];
            float n10 = ck2.x * m2[ii] - ck2.y * m3[ii];
            float n11 = ck2.y * m2[ii] + ck2.x * m3[ii];
            *(float*)((char*)As + a00[ii]) = cj2.x * n00 - cj2.y * n10;
            *(float*)((char*)As + a10[ii]) = cj2.y * n00 + cj2.x * n10;
            *(float*)((char*)As + a01[ii]) = cj2.x * n01 - cj2.y * n11;
            *(float*)((char*)As + a11[ii]) = cj2.y * n01 + cj2.x * n11;
          }
          a00[ii] += 8; if (a00[ii] >= limA[ii]) a00[ii] -= 764;
          a11[ii] += 8; if (a11[ii] >= limA[ii]) a11[ii] -= 764;
          a01[ii] += 8; if (a01[ii] >= limB[ii]) a01[ii] -= 764;
          a10[ii] += 8; if (a10[ii] >= limB[ii]) a10[ii] -= 764;
        }
      }
      BAR_LGKM();
    }
  }
}

// ---------------- replay fp32 rotations -> Q (fp64, raw orientation) ------
__global__ __launch_bounds__(128) void k_replayA(const float2* __restrict__ rlogA,
                                                 double* __restrict__ Q) {
  __shared__ double vr[CH];
  int row = blockIdx.x, t = threadIdx.x;
  const int NR = SW32 * CH;
  for (int j = t; j < CH; j += 128) vr[j] = (j == row) ? 1.0 : 0.0;
  bool act = (t < 95);
  float2 nb[4];
  #pragma unroll
  for (int u = 0; u < 4; ++u)
    nb[u] = (act && u < NR) ? rlogA[(size_t)u * 95 + t] : make_float2(1.f, 0.f);
  BAR_LGKM();
  int r = 0;
  for (int g = 0; g < NR; g += 4) {
    #pragma unroll
    for (int u = 0; u < 4; ++u) {
      float2 cur = nb[u];
      int gn = g + u + 4;
      nb[u] = (act && gn < NR) ? rlogA[(size_t)gn * 95 + t] : make_float2(1.f, 0.f);
      if (act && cur.y != 0.f) {
        int k = t + 1;
        int p = r + k; if (p >= CH) p -= CH;
        int q = r - k; if (q < 0) q += CH;
        double s = (double)cur.y;
        double c = sqrt(fmax(0.0, 1.0 - s * s));
        double vp = vr[p], vq = vr[q];
        vr[p] = c * vp - s * vq;
        vr[q] = s * vp + c * vq;
      }
      if (++r == CH) r = 0;
      BAR_LGKM();
    }
  }
  for (int j = t; j < CH; j += 128) Q[(size_t)row * CH + j] = vr[j];
}

// ---------------- A' = Q^T G Q (fp64, exact repair of fp32 stage) ---------
__global__ void k_gq(const double* __restrict__ G64, const double* __restrict__ Q,
                     double* __restrict__ T) {
  int j = blockIdx.x * 16 + threadIdx.x, i = blockIdx.y * 16 + threadIdx.y;
  if (i >= CH || j >= CH) return;
  double acc = 0;
  for (int k = 0; k < CH; ++k) acc += G64[i * CH + k] * Q[(size_t)k * CH + j];
  T[i * CH + j] = acc;
}
__global__ void k_qtq(const double* __restrict__ Q, const double* __restrict__ T,
                      double* __restrict__ A2sk, double* __restrict__ dg64) {
  int j = blockIdx.x * 16 + threadIdx.x, i = blockIdx.y * 16 + threadIdx.y;
  if (i >= CH || j >= CH || j < i) return;
  double acc = 0;
  for (int k = 0; k < CH; ++k) acc += Q[(size_t)k * CH + i] * T[k * CH + j];
  if (j == i) dg64[i] = acc;
  else A2sk[sk(i, j)] = acc;
}

// ---------------- stage D: fp64 polish Jacobi (exactly 1 sweep) -----------
__global__ __launch_bounds__(1024) void k_jac64(const double* __restrict__ A2sk,
                                                const double* __restrict__ dg0,
                                                double* __restrict__ eig,
                                                double2* __restrict__ rlogB) {
  extern __shared__ double As64[];
  __shared__ double2 csn[96];
  __shared__ double dg[CH];
  int t = threadIdx.x;

  int jS[5], kS[5]; int ntask = 0;
  for (int id = t; id < 4560; id += 1024) {
    int j = 0, off = 0;
    while (off + (95 - j) <= id) { off += 95 - j; ++j; }
    jS[ntask] = j; kS[ntask] = j + 1 + (id - off);
    ++ntask;
  }
  int a00[5], a01[5], a10[5], a11[5], limA[5], limB[5];
  #pragma unroll
  for (int ii = 0; ii < 5; ++ii) {
    if (ii < ntask) {
      int j = jS[ii], k = kS[ii];
      int A = j + k;
      int B = k - j;
      int dfB = (A > 95) ? (CH - A) : A;
      int bA = B * 194;
      int bB = dfB * 194;
      a00[ii] = (bA + A) * 8;
      a11[ii] = (bA + CH - A) * 8;
      a01[ii] = (bB + CH - B) * 8;
      a10[ii] = (bB + B) * 8;
      limA[ii] = (bA + CH) * 8;
      limB[ii] = (bB + CH) * 8;
    } else {
      a00[ii] = a01[ii] = a10[ii] = a11[ii] = 0;
      limA[ii] = limB[ii] = 1 << 30; jS[ii] = 0; kS[ii] = 1;
    }
  }

  for (int e = t; e < NSKEW; e += 1024) As64[e] = A2sk[e];
  if (t < CH) dg[t] = dg0[t];
  __syncthreads();

  const char* Asb = (const char*)As64;
  for (int r = 0; r < CH; ++r) {
    double m0[5], m1[5], m2[5], m3[5];
    #pragma unroll
    for (int ii = 0; ii < 5; ++ii) {
      if (ii < ntask) {
        m0[ii] = *(const double*)(Asb + a00[ii]);
        m1[ii] = *(const double*)(Asb + a01[ii]);
        if (jS[ii] != 0) {
          m2[ii] = *(const double*)(Asb + a10[ii]);
          m3[ii] = *(const double*)(Asb + a11[ii]);
        }
      }
    }
    if (t >= 1 && t < 96) {
      int p = r + t; if (p >= CH) p -= CH;
      int q = r - t; if (q < 0) q += CH;
      int ipq = sk(p, q);
      double app = dg[p], aqq = dg[q], apq = As64[ipq];
      double c = 1.0, s = 0.0, piv = apq, dp = app, dq = aqq;
      if (fabs(apq) > 4e-16 * (fabs(app) + fabs(aqq)) + 1e-300) {
        double tau = (aqq - app) / (2.0 * apq);
        double tt = copysign(1.0, tau) / (fabs(tau) + sqrt(1.0 + tau * tau));
        c = 1.0 / sqrt(1.0 + tt * tt); s = tt * c;
        dp = app - tt * apq; dq = aqq + tt * apq; piv = 0.0;
      }
      dg[p] = dp; dg[q] = dq;
      As64[ipq] = piv;
      csn[t] = make_double2(c, s);
      rlogB[(size_t)r * 95 + (t - 1)] = make_double2(c, s);
    }
    BAR_LGKM();
    #pragma unroll
    for (int ii = 0; ii < 5; ++ii) {
      if (ii < ntask) {
        double2 ck2 = csn[kS[ii]];
        if (jS[ii] == 0) {
          double vp = m0[ii], vq = m1[ii];
          *(double*)((char*)As64 + a00[ii]) = ck2.x * vp - ck2.y * vq;
          *(double*)((char*)As64 + a01[ii]) = ck2.y * vp + ck2.x * vq;
        } else {
          double2 cj2 = csn[jS[ii]];
          double n00 = ck2.x * m0[ii] - ck2.y * m1[ii];
          double n01 = ck2.y * m0[ii] + ck2.x * m1[ii];
          double n10 = ck2.x * m2[ii] - ck2.y * m3[ii];
          double n11 = ck2.y * m2[ii] + ck2.x * m3[ii];
          *(double*)((char*)As64 + a00[ii]) = cj2.x * n00 - cj2.y * n10;
          *(double*)((char*)As64 + a10[ii]) = cj2.y * n00 + cj2.x * n10;
          *(double*)((char*)As64 + a01[ii]) = cj2.x * n01 - cj2.y * n11;
          *(double*)((char*)As64 + a11[ii]) = cj2.y * n01 + cj2.x * n11;
        }
        a00[ii] += 16; if (a00[ii] >= limA[ii]) a00[ii] -= 1528;
        a11[ii] += 16; if (a11[ii] >= limA[ii]) a11[ii] -= 1528;
        a01[ii] += 16; if (a01[ii] >= limB[ii]) a01[ii] -= 1528;
        a10[ii] += 16; if (a10[ii] >= limB[ii]) a10[ii] -= 1528;
      }
    }
    BAR_LGKM();
  }
  for (int i = t; i < CH; i += 1024) eig[i] = dg[i];
}

// ---------------- apply stage-D rotations to Q rows -> V ------------------
__global__ __launch_bounds__(128) void k_replayB(const double2* __restrict__ rlogB,
                                                 const double* __restrict__ Q,
                                                 double* __restrict__ V) {
  __shared__ double vr[CH];
  int row = blockIdx.x, t = threadIdx.x;
  const int NR = CH;
  for (int j = t; j < CH; j += 128) vr[j] = Q[(size_t)row * CH + j];
  double2 nxt = (t < 95) ? rlogB[t] : make_double2(1.0, 0.0);
  BAR_LGKM();
  for (int g = 0; g < NR; ++g) {
    double2 cur = nxt;
    if (t < 95 && g + 1 < NR) nxt = rlogB[(size_t)(g + 1) * 95 + t];
    if (t < 95 && cur.y != 0.0) {
      int k = t + 1;
      int p = g + k; if (p >= CH) p -= CH;
      int q = g - k; if (q < 0) q += CH;
      double vp = vr[p], vq = vr[q];
      vr[p] = cur.x * vp - cur.y * vq;
      vr[q] = cur.y * vp + cur.x * vq;
    }
    BAR_LGKM();
  }
  for (int j = t; j < CH; j += 128) V[(size_t)row * CH + j] = vr[j];
}

// ---------------- sort eigenpairs (desc) + whitened eigvec matrix ---------
__global__ __launch_bounds__(256) void k_sortprep(const double* __restrict__ eig,
                                                  const double* __restrict__ V,
                                                  const double* __restrict__ invs,
                                                  int* __restrict__ perm,
                                                  float* __restrict__ Vw) {
  __shared__ double ev[CH];
  __shared__ int pm[CH];
  int t = threadIdx.x;
  if (t < CH) ev[t] = eig[t];
  __syncthreads();
  if (t < CH) {
    double my = ev[t];
    int rk = 0;
    for (int j = 0; j < CH; ++j) {
      double o = ev[j];
      rk += (o > my || (o == my && j < t)) ? 1 : 0;
    }
    pm[rk] = t;
  }
  __syncthreads();
  if (t < CH) perm[t] = pm[t];
  for (int e = t; e < 192 * 192; e += 256) {
    int k = e / 192, i = e - k * 192;
    float v = 0.f;
    if (k < CH && i < CH) v = (float)(invs[k] * V[(size_t)k * CH + pm[i]]);
    Vw[e] = v;
  }
}

// ---------------- pcT = (Y V)^T : [CH][NPIX] ----------------
__global__ __launch_bounds__(256) void k_pc(const float* __restrict__ x,
                                            const float* __restrict__ Vw,
                                            float* __restrict__ pcT) {
  __shared__ float xs[16][65];
  __shared__ float vs[16][33];
  int n0 = blockIdx.x * 64, i0 = blockIdx.y * 32;
  int t = threadIdx.x;
  int tn = t & 15, ti = t >> 4;
  float acc[4][2] = {};
  for (int k0 = 0; k0 < 192; k0 += 16) {
    {
      int col = t & 15, row = t >> 4;
      #pragma unroll
      for (int rr = 0; rr < 4; ++rr) {
        int nn = row + rr * 16;
        int k = k0 + col;
        xs[col][nn] = (k < CH) ? x[(size_t)(n0 + nn) * CH + k] : 0.f;
      }
    }
    {
      int ii = t & 31, kk = t >> 5;
      vs[kk][ii] = Vw[(k0 + kk) * 192 + i0 + ii];
      vs[kk + 8][ii] = Vw[(k0 + kk + 8) * 192 + i0 + ii];
    }
    __syncthreads();
    #pragma unroll
    for (int kk = 0; kk < 16; ++kk) {
      float b0 = vs[kk][ti], b1 = vs[kk][ti + 16];
      #pragma unroll
      for (int rr = 0; rr < 4; ++rr) {
        float a = xs[kk][tn + rr * 16];
        acc[rr][0] += a * b0;
        acc[rr][1] += a * b1;
      }
    }
    __syncthreads();
  }
  #pragma unroll
  for (int rr = 0; rr < 4; ++rr)
    #pragma unroll
    for (int bb = 0; bb < 2; ++bb) {
      int i = i0 + ti + bb * 16, n = n0 + tn + rr * 16;
      if (i < CH) pcT[(size_t)i * NPIX + n] = acc[rr][bb];
    }
}

// ---------------- DWT row pass (level 1 only) ----------------
__global__ __launch_bounds__(256) void k_row(const float* __restrict__ in,
                                             float* __restrict__ rb,
                                             int h, int w, int wd, int chS) {
  __shared__ float rowv[256];
  int bid = blockIdx.x;
  int c = bid / h, y = bid % h;
  const float* src = in + (size_t)c * chS + (size_t)y * w;
  int t = threadIdx.x;
  if (t < w) rowv[t] = src[t];
  __syncthreads();
  float* dst = rb + (size_t)(c * h + y) * (2 * wd);
  for (int o = t; o < 2 * wd; o += 256) {
    int b = (o >= wd) ? 1 : 0;
    int xp = b ? o - wd : o;
    float acc = 0.f;
    #pragma unroll
    for (int s = 0; s < 10; ++s) {
      int m = 2 * xp + 1 - s;
      if (m < 0) m = -1 - m;
      else if (m >= w) m = 2 * w - 1 - m;
      acc += (b ? g_dhi[s] : g_dlo[s]) * rowv[m];
    }
    dst[o] = acc;
  }
}

// ---------------- DWT column pass (level 1 only) -----------
__global__ __launch_bounds__(256) void k_col(const float* __restrict__ rb,
                                             float* __restrict__ llout,
                                             float* __restrict__ coeff,
                                             int h, int wd, int hd, int chSout,
                                             int offHi, int offLL, int lastlvl) {
  int c = blockIdx.z, yp = blockIdx.y;
  int xq = blockIdx.x * 256 + threadIdx.x;
  if (xq >= 2 * wd) return;
  const float* base = rb + (size_t)c * h * 2 * wd + xq;
  float lo = 0.f, hi = 0.f;
  #pragma unroll
  for (int s = 0; s < 10; ++s) {
    int m = 2 * yp + 1 - s;
    if (m < 0) m = -1 - m;
    else if (m >= h) m = 2 * h - 1 - m;
    float v = base[(size_t)m * 2 * wd];
    lo += g_dlo[s] * v;
    hi += g_dhi[s] * v;
  }
  float* cc = coeff + (size_t)c * CSTRIDE;
  if (xq < wd) {
    llout[(size_t)c * chSout + (size_t)yp * wd + xq] = lo;
    if (lastlvl) cc[offLL + yp * wd + xq] = lo;
    cc[offHi + 0 * hd * wd + yp * wd + xq] = hi;
  } else {
    int xp = xq - wd;
    cc[offHi + 1 * hd * wd + yp * wd + xp] = lo;
    cc[offHi + 2 * hd * wd + yp * wd + xp] = hi;
  }
}

// ---------------- DWT levels 2-5 fused: LDS-resident cascade --------------
#define DWT_SMEM ((17424 + 18480) * 4)
__global__ __launch_bounds__(256) void k_dwt_tail(const float* __restrict__ llin,
                                                  float* __restrict__ coeff) {
  extern __shared__ float smem[];
  float* A = smem;
  float* B = smem + 17424;
  const int hsz[5]   = {132, 70, 39, 24, 16};
  const int offHiC[4] = {52272, 66972, 71535, 73263};
  int c = blockIdx.x, t = threadIdx.x;
  float* cc = coeff + (size_t)c * CSTRIDE;
  for (int e = t; e < 132 * 132; e += 256) A[e] = llin[(size_t)c * 17424 + e];
  BAR_LGKM();
  #pragma unroll
  for (int l = 0; l < 4; ++l) {
    const int h = hsz[l], w = hsz[l], wd = hsz[l + 1], hd = hsz[l + 1];
    const int w2 = 2 * wd;
    for (int e = t; e < h * w2; e += 256) {
      int y = e / w2, o = e - y * w2;
      int b = (o >= wd) ? 1 : 0;
      int xp = b ? o - wd : o;
      float acc = 0.f;
      #pragma unroll
      for (int s = 0; s < 10; ++s) {
        int m = 2 * xp + 1 - s;
        if (m < 0) m = -1 - m;
        else if (m >= w) m = 2 * w - 1 - m;
        acc += (b ? g_dhi[s] : g_dlo[s]) * A[y * w + m];
      }
      B[y * w2 + o] = acc;
    }
    BAR_LGKM();
    for (int e = t; e < hd * w2; e += 256) {
      int yp = e / w2, xq = e - yp * w2;
      float lo = 0.f, hi = 0.f;
      #pragma unroll
      for (int s = 0; s < 10; ++s) {
        int m = 2 * yp + 1 - s;
        if (m < 0) m = -1 - m;
        else if (m >= h) m = 2 * h - 1 - m;
        float v = B[m * w2 + xq];
        lo += g_dlo[s] * v;
        hi += g_dhi[s] * v;
      }
      if (xq < wd) {
        A[yp * wd + xq] = lo;
        if (l == 3) cc[74031 + yp * wd + xq] = lo;
        cc[offHiC[l] + 0 * hd * wd + yp * wd + xq] = hi;
      } else {
        int xp = xq - wd;
        cc[offHiC[l] + 1 * hd * wd + yp * wd + xp] = lo;
        cc[offHiC[l] + 2 * hd * wd + yp * wd + xp] = hi;
      }
    }
    BAR_LGKM();
  }
}

// ---------------- SURE statistics (per-thread accumulate, then reduce) ----
__global__ __launch_bounds__(256) void k_stats(const float* __restrict__ coeff,
                                               double* __restrict__ stats, TArgs ta) {
  int c = blockIdx.y;
  const float* cc = coeff + (size_t)c * CSTRIDE;
  double sm[15], cnt[15], nrm = 0;
  #pragma unroll
  for (int q = 0; q < 15; ++q) { sm[q] = 0; cnt[q] = 0; }
  for (int idx = blockIdx.x * 256 + threadIdx.x; idx < MCOEF; idx += 24 * 256) {
    double v = (double)cc[idx];
    double v2 = v * v;
    nrm += v2;
    #pragma unroll
    for (int q = 0; q < 15; ++q) {
      sm[q] += fmin(v2, ta.t2[q]);
      cnt[q] += (v2 >= ta.t2[q]) ? 1.0 : 0.0;
    }
  }
  __shared__ double wred[4][31];
  int lane = threadIdx.x & 63, wv = threadIdx.x >> 6;
  for (int q = 0; q < 31; ++q) {
    double val = (q < 15) ? sm[q] : ((q < 30) ? cnt[q - 15] : nrm);
    #pragma unroll
    for (int o = 32; o > 0; o >>= 1) val += __shfl_down(val, o);
    if (lane == 0) wred[wv][q] = val;
  }
  __syncthreads();
  if (threadIdx.x < 31) {
    double sum = wred[0][threadIdx.x] + wred[1][threadIdx.x] +
                 wred[2][threadIdx.x] + wred[3][threadIdx.x];
    atomicAdd(&stats[c * 31 + threadIdx.x], sum);
  }
}

// ---------------- SURE scan + rank + masked projection matrix -------------
__global__ __launch_bounds__(256) void k_sure(const double* __restrict__ stats,
                                              const double* __restrict__ sqrtom,
                                              const double* __restrict__ V,
                                              const int* __restrict__ perm,
                                              const int* __restrict__ min_iter_p,
                                              float* __restrict__ Wm,
                                              int* __restrict__ meta) {
  __shared__ double st[CH * 31];
  __shared__ double minsure[CH];
  __shared__ int rankS;
  int t = threadIdx.x;
  for (int e = t; e < CH * 31; e += 256) st[e] = stats[e];
  __syncthreads();
  if (t == 0) {
    double norm2 = 0;
    for (int c = 0; c < CH; ++c) norm2 += st[c * 31 + 30];
    double K = norm2 - (double)MCOEF * (double)CH;
    double cum[15];
    for (int q = 0; q < 15; ++q) cum[q] = 0;
    for (int r = 0; r < CH; ++r) {
      double mn = 1e300;
      for (int q = 0; q < 15; ++q) {
        double sure = st[r * 31 + q] + 2.0 * st[r * 31 + 15 + q] - (double)MCOEF;
        double s = cum[q] + sure + K;
        cum[q] += s;
        if (s < mn) mn = s;
      }
      minsure[r] = mn;
    }
    int mi = *min_iter_p;
    int rank = CH - 1;
    for (int r = 0; r < CH; ++r) {
      double prev = (r == 0) ? minsure[0] : minsure[r - 1];
      bool cond = (r > mi) && !(minsure[r] > 2.0 * prev);
      if (cond) { rank = r; break; }
    }
    rankS = rank;
    meta[1] = rank;
  }
  __syncthreads();
  int rank = rankS;
  for (int e = t; e < 192 * 192; e += 256) {
    int k = e / 192, c = e - k * 192;
    float v = 0.f;
    if (k < rank && c < CH) v = (float)(sqrtom[c] * V[(size_t)c * CH + perm[k]]);
    Wm[e] = v;
  }
}

// ---------------- out = pcT^T * Wm ----------------
__global__ __launch_bounds__(256) void k_out(const float* __restrict__ pcT,
                                             const float* __restrict__ Wm,
                                             float* __restrict__ out) {
  __shared__ float psx[16][65];
  __shared__ float wsx[16][33];
  int n0 = blockIdx.x * 64, c0 = blockIdx.y * 32;
  int t = threadIdx.x;
  int tc = t & 15, tn = t >> 4;
  float acc[4][2] = {};
  for (int k0 = 0; k0 < 192; k0 += 16) {
    {
      int nn = t & 63, kk0 = t >> 6;
      #pragma unroll
      for (int rr = 0; rr < 4; ++rr) {
        int kk = kk0 + rr * 4;
        int k = k0 + kk;
        psx[kk][nn] = (k < CH) ? pcT[(size_t)k * NPIX + n0 + nn] : 0.f;
      }
    }
    {
      int cc = t & 31, kk = t >> 5;
      wsx[kk][cc] = Wm[(k0 + kk) * 192 + c0 + cc];
      wsx[kk + 8][cc] = Wm[(k0 + kk + 8) * 192 + c0 + cc];
    }
    __syncthreads();
    #pragma unroll
    for (int kk = 0; kk < 16; ++kk) {
      float b0 = wsx[kk][tc], b1 = wsx[kk][tc + 16];
      #pragma unroll
      for (int rr = 0; rr < 4; ++rr) {
        float a = psx[kk][tn + rr * 16];
        acc[rr][0] += a * b0;
        acc[rr][1] += a * b1;
      }
    }
    __syncthreads();
  }
  #pragma unroll
  for (int rr = 0; rr < 4; ++rr)
    #pragma unroll
    for (int bb = 0; bb < 2; ++bb) {
      int n = n0 + tn + rr * 16, c = c0 + tc + bb * 16;
      if (c < CH) out[(size_t)n * CH + c] = acc[rr][bb];
    }
}

// ---------------- host ----------------
extern "C" void kernel_launch(void* const* d_in, const int* in_sizes, int n_in,
                              void* d_out, int out_size, void* d_ws, size_t ws_size,
                              hipStream_t stream) {
  const float* x = (const float*)d_in[0];
  const int* p_min_iter = (const int*)d_in[1];
  float* out = (float*)d_out;
  char* ws = (char*)d_ws;

  size_t cur = 0;
  auto A = [&](size_t b) { size_t o = cur; cur += (b + 511) & ~(size_t)511; return o; };
  double* ddp     = (double*)(ws + A((size_t)CH * CH * 8));
  double* ddpi64  = (double*)(ws + A((size_t)CH * CH * 8));
  double* Tm      = (double*)(ws + A((size_t)CH * CH * 8));
  double* V       = (double*)(ws + A((size_t)CH * CH * 8));
  double* G64     = (double*)(ws + A((size_t)CH * CH * 8));
  double* T64     = (double*)(ws + A((size_t)CH * CH * 8));
  double* Q       = (double*)(ws + A((size_t)CH * CH * 8));
  double* A2sk    = (double*)(ws + A((size_t)NSKEW * 8));
  double* dg64    = (double*)(ws + A((size_t)CH * 8));
  double* eig     = (double*)(ws + A((size_t)CH * 8));
  double* rsum    = (double*)(ws + A((size_t)CH * 8));
  double* sqrtom  = (double*)(ws + A((size_t)CH * 8));
  double* invs    = (double*)(ws + A((size_t)CH * 8));
  double* stats   = (double*)(ws + A((size_t)CH * 31 * 8));
  int* perm       = (int*)(ws + A((size_t)CH * 4));
  int* meta       = (int*)(ws + A(64));
  float* ddpi32   = (float*)(ws + A((size_t)CH * CH * 4));
  float* Gsk      = (float*)(ws + A((size_t)NSKEW * 4));
  float* dgf      = (float*)(ws + A((size_t)CH * 4));
  float* Vw       = (float*)(ws + A((size_t)192 * 192 * 4));
  float* Wm       = (float*)(ws + A((size_t)192 * 192 * 4));
  float2* rlogA   = (float2*)(ws + A((size_t)SW32 * CH * 95 * 8));
  double2* rlogB  = (double2*)(ws + A((size_t)CH * 95 * 16));
  float* pcT      = (float*)(ws + A((size_t)CH * NPIX * 4));
  float* rowbuf   = (float*)(ws + A((size_t)CH * 256 * 264 * 4));
  float* llA      = (float*)(ws + A((size_t)CH * 17424 * 4));
  float* coeff    = (float*)(ws + A((size_t)CH * CSTRIDE * 4));
  (void)ws_size; (void)in_sizes; (void)n_in; (void)out_size;

  hipMemsetAsync(ddp, 0, (size_t)CH * CH * 8, stream);
  hipMemsetAsync(rsum, 0, (size_t)CH * 8, stream);
  hipMemsetAsync(stats, 0, (size_t)CH * 31 * 8, stream);

  const int J32_SMEM = NSKEW * 4;                               // 74496
  const int J64_SMEM = NSKEW * 8;                               // 148992

  k_ddp<<<dim3(6, 6, 16), 256, 0, stream>>>(x, ddp);
  k_mirror<<<143, 256, 0, stream>>>(ddp);
  k_rsum<<<256, 256, 0, stream>>>(x, rsum);
  k_gj<<<1, 768, 0, stream>>>(ddp, ddpi32);
  k_newton1<<<dim3(12, 12), dim3(16, 16), 0, stream>>>(ddp, ddpi32, Tm);
  k_newton2<<<dim3(12, 12), dim3(16, 16), 0, stream>>>(ddpi32, Tm, ddpi64);
  k_beta<<<CH, 256, 0, stream>>>(ddp, ddpi64, rsum, sqrtom, invs);
  k_packG<<<143, 256, 0, stream>>>(ddp, invs, Gsk, dgf, G64);
  (void)hipFuncSetAttribute((const void*)k_jac32,
        hipFuncAttributeMaxDynamicSharedMemorySize, J32_SMEM);
  k_jac32<<<1, 1024, J32_SMEM, stream>>>(Gsk, dgf, rlogA);
  k_replayA<<<CH, 128, 0, stream>>>(rlogA, Q);
  k_gq<<<dim3(12, 12), dim3(16, 16), 0, stream>>>(G64, Q, T64);
  k_qtq<<<dim3(12, 12), dim3(16, 16), 0, stream>>>(Q, T64, A2sk, dg64);
  (void)hipFuncSetAttribute((const void*)k_jac64,
        hipFuncAttributeMaxDynamicSharedMemorySize, J64_SMEM);
  k_jac64<<<1, 1024, J64_SMEM, stream>>>(A2sk, dg64, eig, rlogB);
  k_replayB<<<CH, 128, 0, stream>>>(rlogB, Q, V);
  k_sortprep<<<1, 256, 0, stream>>>(eig, V, invs, perm, Vw);
  k_pc<<<dim3(1024, 6), 256, 0, stream>>>(x, Vw, pcT);

  // DWT level 1 (256 -> 132) via row/col, then levels 2-5 fused in LDS
  k_row<<<CH * 256, 256, 0, stream>>>(pcT, rowbuf, 256, 256, 132, NPIX);
  k_col<<<dim3(2, 132, CH), 256, 0, stream>>>(
      rowbuf, llA, coeff, 256, 132, 132, 132 * 132, 0, 74031, 0);
  (void)hipFuncSetAttribute((const void*)k_dwt_tail,
        hipFuncAttributeMaxDynamicSharedMemorySize, DWT_SMEM);
  k_dwt_tail<<<CH, 256, DWT_SMEM, stream>>>(llA, coeff);

  TArgs ta;
  {
    double tmax = sqrt(log((double)MCOEF));
    for (int j = 0; j < 15; ++j) { double tv = tmax * j / 14.0; ta.t2[j] = tv * tv; }
  }
  k_stats<<<dim3(24, CH), 256, 0, stream>>>(coeff, stats, ta);
  k_sure<<<1, 256, 0, stream>>>(stats, sqrtom, V, perm, p_min_iter, Wm, meta);
  k_out<<<dim3(1024, 6), 256, 0, stream>>>(pcT, Wm, out);
}

// Round 15
// 3583.314 us; speedup vs baseline: 1.2424x; 1.0236x over previous
//
#include <hip/hip_runtime.h>
#include <math.h>
#include <cstdint>

// ---------------- constants ----------------
#define CH 191
#define NPIX 65536
#define MCOEF 74287            // total wavelet coeffs per channel
#define CSTRIDE 74288
#define SW32 4                 // fp32 Jacobi sweeps. Lever CLOSED at 4 (R10).
// (fold(a-b), (a+b) mod 191) layout: addr = df*194 + s, df in [0,95], s in [0,191)
#define NSKEW (96 * 194)       // 18624 elements

__device__ const float g_dlo[10] = {
  0.003335725285001549f, -0.012580751999015526f, -0.006241490213011705f,
  0.07757149384006515f, -0.03224486958502952f, -0.24229488706619015f,
  0.13842814590110342f, 0.7243085284385744f, 0.6038292697974729f,
  0.160102397974125f };
__device__ const float g_dhi[10] = {
  -0.160102397974125f, 0.6038292697974729f, -0.7243085284385744f,
  0.13842814590110342f, 0.24229488706619015f, -0.03224486958502952f,
  -0.07757149384006515f, -0.006241490213011705f, 0.012580751999015526f,
  0.003335725285001549f };

struct TArgs { double t2[15]; };

__device__ __forceinline__ int sk(int a, int b) {
  int s = a + b; if (s >= CH) s -= CH;
  int d = a - b; if (d < 0) d = -d;
  int df = (d > 95) ? (CH - d) : d;
  return df * 194 + s;
}

#define BAR_LGKM() asm volatile("s_waitcnt lgkmcnt(0)\n\ts_barrier" ::: "memory")

// ---------------- ddp = X^T X (fp64 accum) ----------------
__global__ __launch_bounds__(256) void k_ddp(const float* __restrict__ x,
                                             double* __restrict__ ddp) {
  __shared__ float as[32][33];
  __shared__ float bs[32][33];
  int i0 = blockIdx.x * 32, j0 = blockIdx.y * 32;
  if (j0 < i0) return;
  int t = threadIdx.x;
  int n0 = blockIdx.z * 4096;
  int tx = t & 15, ty = t >> 4;
  double a00 = 0, a01 = 0, a10 = 0, a11 = 0;
  for (int nb = 0; nb < 4096; nb += 32) {
    for (int e = t; e < 1024; e += 256) {
      int kk = e >> 5, ii = e & 31;
      int n = n0 + nb + kk;
      as[kk][ii] = (i0 + ii < CH) ? x[(size_t)n * CH + i0 + ii] : 0.f;
      bs[kk][ii] = (j0 + ii < CH) ? x[(size_t)n * CH + j0 + ii] : 0.f;
    }
    __syncthreads();
    #pragma unroll 8
    for (int kk = 0; kk < 32; ++kk) {
      double x0 = as[kk][tx], x1 = as[kk][tx + 16];
      double y0 = bs[kk][ty], y1 = bs[kk][ty + 16];
      a00 += x0 * y0; a01 += x0 * y1; a10 += x1 * y0; a11 += x1 * y1;
    }
    __syncthreads();
  }
  int i = i0 + tx, j = j0 + ty;
  if (i < CH) {
    if (j < CH)      atomicAdd(&ddp[i * CH + j], a00);
    if (j + 16 < CH) atomicAdd(&ddp[i * CH + j + 16], a01);
  }
  if (i + 16 < CH) {
    if (j < CH)      atomicAdd(&ddp[(i + 16) * CH + j], a10);
    if (j + 16 < CH) atomicAdd(&ddp[(i + 16) * CH + j + 16], a11);
  }
}

__global__ void k_mirror(double* __restrict__ ddp) {
  int e = blockIdx.x * 256 + threadIdx.x;
  if (e >= CH * CH) return;
  int i = e / CH, j = e % CH;
  if (i > j) ddp[e] = ddp[j * CH + i];
}

__global__ __launch_bounds__(256) void k_rsum(const float* __restrict__ x,
                                              double* __restrict__ rsum) {
  int t = threadIdx.x;
  if (t >= CH) return;
  int row0 = blockIdx.x * 256;
  double a = 0;
  for (int r = 0; r < 256; ++r) a += (double)x[(size_t)(row0 + r) * CH + t];
  atomicAdd(&rsum[t], a);
}

// ---------------- fp32 approximate inverse via symmetric SWEEP ----------------
// FROZEN at R9's version (proven ~380us across R9/R10/R11/R14). R12/R13's
// variant re-triggered the register-spill cliff (+780us).
__global__ __launch_bounds__(768) void k_gj(const double* __restrict__ ddp,
                                            float* __restrict__ out) {
  __shared__ float fc[192];
  int t = threadIdx.x;
  int i = t % 192;        // row
  int cg = t / 192;       // column group: cols j = cg*48 + m
  int j0 = cg * 48;
  bool act = (i < CH);
  float a[48];
  #pragma unroll
  for (int m = 0; m < 48; ++m) {
    int j = j0 + m;
    a[m] = (act && j < CH) ? (float)(ddp[i * CH + j] + ((i == j) ? 1e-6 : 0.0)) : 0.f;
  }
  if (t < 192) fc[t] = 0.f;          // fc[191] stays 0 (pad row no-op)
  __syncthreads();
  for (int k = 0; k < CH; ++k) {
    int cgk = k / 48;                // wave-uniform across each cg's 3 waves
    int mk = k - cgk * 48;
    if (cg == cgk && act) {
      float v = 0.f;
      #pragma unroll
      for (int m = 0; m < 48; ++m) v = (m == mk) ? a[m] : v;   // static idx
      fc[i] = v;
    }
    __syncthreads();
    float dinv = 1.0f / fc[k];
    float fci = fc[i];
    bool iskrow = (i == k);
    float s = fci * dinv;
    float colv = iskrow ? (-dinv) : s;   // b_kk = -1/d ; b_ik = a_ik/d
    #pragma unroll
    for (int mq = 0; mq < 12; ++mq) {
      float4 f4 = *(const float4*)&fc[j0 + mq * 4];
      #pragma unroll
      for (int c4 = 0; c4 < 4; ++c4) {
        int m = mq * 4 + c4;
        float fj = (c4 == 0) ? f4.x : (c4 == 1) ? f4.y : (c4 == 2) ? f4.z : f4.w;
        float gen = iskrow ? (fj * dinv) : (a[m] - s * fj);
        bool iskcol = (cg == cgk) && (m == mk);
        a[m] = iskcol ? colv : gen;
      }
    }
    __syncthreads();
  }
  if (act) {
    #pragma unroll
    for (int m = 0; m < 48; ++m) {
      int j = j0 + m;
      if (j < CH) out[i * CH + j] = -a[m];
    }
  }
}

// ---------------- one Newton refinement step: P = X(2I - A X), fp64 -------
__global__ void k_newton1(const double* __restrict__ ddp, const float* __restrict__ X,
                          double* __restrict__ T) {
  int j = blockIdx.x * 16 + threadIdx.x, i = blockIdx.y * 16 + threadIdx.y;
  if (i >= CH || j >= CH) return;
  double acc = 0;
  for (int k = 0; k < CH; ++k) {
    double a = ddp[i * CH + k] + (i == k ? 1e-6 : 0.0);
    acc += a * (double)X[k * CH + j];
  }
  T[i * CH + j] = (i == j ? 2.0 : 0.0) - acc;
}
__global__ void k_newton2(const float* __restrict__ X, const double* __restrict__ T,
                          double* __restrict__ P) {
  int j = blockIdx.x * 16 + threadIdx.x, i = blockIdx.y * 16 + threadIdx.y;
  if (i >= CH || j >= CH) return;
  double acc = 0;
  for (int k = 0; k < CH; ++k) acc += (double)X[i * CH + k] * T[k * CH + j];
  P[i * CH + j] = acc;
}

// ---------------- per-band regression -> omega ----------------
__global__ __launch_bounds__(256) void k_beta(const double* __restrict__ ddp,
                                              const double* __restrict__ P,
                                              const double* __restrict__ rsum,
                                              double* __restrict__ sqrtom,
                                              double* __restrict__ invs) {
  __shared__ double bet[CH];
  __shared__ double red[256];
  int i = blockIdx.x, t = threadIdx.x;
  double pii = P[i * CH + i];
  for (int j = t; j < CH; j += 256) {
    double pjip = P[j * CH + i] / pii;
    double acc = 0;
    for (int k = 0; k < CH; ++k) {
      double ddpa = (k == i) ? 0.0 : ddp[k * CH + i];
      acc += (P[j * CH + k] - pjip * P[i * CH + k]) * ddpa;
    }
    bet[j] = (j == i) ? 0.0 : acc;
  }
  __syncthreads();
  double s1 = 0, s2 = 0;
  for (int j = t; j < CH; j += 256) {
    double gj = ((j == i) ? 1.0 : 0.0) - bet[j];
    s1 += gj * rsum[j];
    double tj = 0;
    for (int k = 0; k < CH; ++k) {
      double gk = ((k == i) ? 1.0 : 0.0) - bet[k];
      tj += ddp[j * CH + k] * gk;
    }
    s2 += gj * tj;
  }
  red[t] = s1; __syncthreads();
  for (int o = 128; o; o >>= 1) { if (t < o) red[t] += red[t + o]; __syncthreads(); }
  double sumw = red[0]; __syncthreads();
  red[t] = s2; __syncthreads();
  for (int o = 128; o; o >>= 1) { if (t < o) red[t] += red[t + o]; __syncthreads(); }
  if (t == 0) {
    double sumsq = red[0];
    double var = (sumsq - sumw * sumw / 65536.0) / 65535.0;
    if (var < 0) var = 0;
    double so = sqrt(var) + 1e-30;
    sqrtom[i] = so;
    invs[i] = 1.0 / so;
  }
}

// ---------------- whitened Gram: (df,s)-layout fp32 + diag + full fp64 -----
__global__ void k_packG(const double* __restrict__ ddp, const double* __restrict__ invs,
                        float* __restrict__ Gsk, float* __restrict__ dgf,
                        double* __restrict__ G64) {
  int e = blockIdx.x * 256 + threadIdx.x;
  if (e >= CH * CH) return;
  int i = e / CH, j = e % CH;
  double v = ddp[e] * invs[i] * invs[j];
  G64[e] = v;
  if (j >= i) Gsk[sk(i, j)] = (float)v;
  if (j == i) dgf[i] = (float)v;
}

// ---------------- stage A: single-block fp32 Jacobi (two-phase, R4 struct) --
__global__ __launch_bounds__(1024) void k_jac32(const float* __restrict__ Gsk,
                                                const float* __restrict__ dg0,
                                                float2* __restrict__ rlogA) {
  extern __shared__ float As[];
  __shared__ float2 csn[96];
  __shared__ float dg[CH];
  int t = threadIdx.x;

  int jS[5], kS[5]; int ntask = 0;
  for (int id = t; id < 4560; id += 1024) {
    int j = 0, off = 0;
    while (off + (95 - j) <= id) { off += 95 - j; ++j; }
    jS[ntask] = j; kS[ntask] = j + 1 + (id - off);
    ++ntask;
  }
  int a00[5], a01[5], a10[5], a11[5], limA[5], limB[5];
  #pragma unroll
  for (int ii = 0; ii < 5; ++ii) {
    if (ii < ntask) {
      int j = jS[ii], k = kS[ii];
      int A = j + k;
      int B = k - j;
      int dfB = (A > 95) ? (CH - A) : A;
      int bA = B * 194;
      int bB = dfB * 194;
      a00[ii] = (bA + A) * 4;
      a11[ii] = (bA + CH - A) * 4;
      a01[ii] = (bB + CH - B) * 4;
      a10[ii] = (bB + B) * 4;
      limA[ii] = (bA + CH) * 4;
      limB[ii] = (bB + CH) * 4;
    } else {
      a00[ii] = a01[ii] = a10[ii] = a11[ii] = 0;
      limA[ii] = limB[ii] = 1 << 30; jS[ii] = 0; kS[ii] = 1;
    }
  }

  for (int e = t; e < NSKEW; e += 1024) As[e] = Gsk[e];
  if (t < CH) dg[t] = dg0[t];
  __syncthreads();

  const char* Asb = (const char*)As;
  for (int sweep = 0; sweep < SW32; ++sweep) {
    for (int r = 0; r < CH; ++r) {
      float m0[5], m1[5], m2[5], m3[5];
      #pragma unroll
      for (int ii = 0; ii < 5; ++ii) {
        if (ii < ntask) {
          m0[ii] = *(const float*)(Asb + a00[ii]);
          m1[ii] = *(const float*)(Asb + a01[ii]);
          if (jS[ii] != 0) {
            m2[ii] = *(const float*)(Asb + a10[ii]);
            m3[ii] = *(const float*)(Asb + a11[ii]);
          }
        }
      }
      if (t >= 1 && t < 96) {
        int p = r + t; if (p >= CH) p -= CH;
        int q = r - t; if (q < 0) q += CH;
        int ipq = sk(p, q);
        float app = dg[p], aqq = dg[q], apq = As[ipq];
        float c = 1.0f, s = 0.0f, piv = apq, dp = app, dq = aqq;
        if (fabsf(apq) > 3e-7f * (fabsf(app) + fabsf(aqq)) + 1e-30f) {
          float tau = (aqq - app) / (2.0f * apq);
          float tt = copysignf(1.0f, tau) / (fabsf(tau) + sqrtf(1.0f + tau * tau));
          c = 1.0f / sqrtf(1.0f + tt * tt); s = tt * c;
          dp = app - tt * apq; dq = aqq + tt * apq; piv = 0.0f;
        }
        dg[p] = dp; dg[q] = dq;
        As[ipq] = piv;
        csn[t] = make_float2(c, s);
        rlogA[((size_t)(sweep * CH + r)) * 95 + (t - 1)] = make_float2(c, s);
      }
      BAR_LGKM();
      #pragma unroll
      for (int ii = 0; ii < 5; ++ii) {
        if (ii < ntask) {
          float2 ck2 = csn[kS[ii]];
          if (jS[ii] == 0) {
            float vp = m0[ii], vq = m1[ii];
            *(float*)((char*)As + a00[ii]) = ck2.x * vp - ck2.y * vq;
            *(float*)((char*)As + a01[ii]) = ck2.y * vp + ck2.x * vq;
          } else {
            float2 cj2 = csn[jS[ii]];
            float n00 = ck2.x * m0[ii] - ck2.y * m1[ii];
            float n01 = ck2.y * m0[ii] + ck2.x * m1[ii];
            float n10 = ck2.x * m2[ii] - ck2.y * m3[ii];
            float n11 = ck2.y * m2[ii] + ck2.x * m3[ii];
            *(float*)((char*)As + a00[ii]) = cj2.x * n00 - cj2.y * n10;
            *(float*)((char*)As + a10[ii]) = cj2.y * n00 + cj2.x * n10;
            *(float*)((char*)As + a01[ii]) = cj2.x * n01 - cj2.y * n11;
            *(float*)((char*)As + a11[ii]) = cj2.y * n01 + cj2.x * n11;
          }
          a00[ii] += 8; if (a00[ii] >= limA[ii]) a00[ii] -= 764;
          a11[ii] += 8; if (a11[ii] >= limA[ii]) a11[ii] -= 764;
          a01[ii] += 8; if (a01[ii] >= limB[ii]) a01[ii] -= 764;
          a10[ii] += 8; if (a10[ii] >= limB[ii]) a10[ii] -= 764;
        }
      }
      BAR_LGKM();
    }
  }
}

// ---------------- replay fp32 rotations -> Q (fp64, raw orientation) ------
__global__ __launch_bounds__(128) void k_replayA(const float2* __restrict__ rlogA,
                                                 double* __restrict__ Q) {
  __shared__ double vr[CH];
  int row = blockIdx.x, t = threadIdx.x;
  const int NR = SW32 * CH;
  for (int j = t; j < CH; j += 128) vr[j] = (j == row) ? 1.0 : 0.0;
  bool act = (t < 95);
  float2 nb[4];
  #pragma unroll
  for (int u = 0; u < 4; ++u)
    nb[u] = (act && u < NR) ? rlogA[(size_t)u * 95 + t] : make_float2(1.f, 0.f);
  BAR_LGKM();
  int r = 0;
  for (int g = 0; g < NR; g += 4) {
    #pragma unroll
    for (int u = 0; u < 4; ++u) {
      float2 cur = nb[u];
      int gn = g + u + 4;
      nb[u] = (act && gn < NR) ? rlogA[(size_t)gn * 95 + t] : make_float2(1.f, 0.f);
      if (act && cur.y != 0.f) {
        int k = t + 1;
        int p = r + k; if (p >= CH) p -= CH;
        int q = r - k; if (q < 0) q += CH;
        double s = (double)cur.y;
        double c = sqrt(fmax(0.0, 1.0 - s * s));
        double vp = vr[p], vq = vr[q];
        vr[p] = c * vp - s * vq;
        vr[q] = s * vp + c * vq;
      }
      if (++r == CH) r = 0;
      BAR_LGKM();
    }
  }
  for (int j = t; j < CH; j += 128) Q[(size_t)row * CH + j] = vr[j];
}

// ---------------- A' = Q^T G Q (fp64, exact repair of fp32 stage) ---------
__global__ void k_gq(const double* __restrict__ G64, const double* __restrict__ Q,
                     double* __restrict__ T) {
  int j = blockIdx.x * 16 + threadIdx.x, i = blockIdx.y * 16 + threadIdx.y;
  if (i >= CH || j >= CH) return;
  double acc = 0;
  for (int k = 0; k < CH; ++k) acc += G64[i * CH + k] * Q[(size_t)k * CH + j];
  T[i * CH + j] = acc;
}
__global__ void k_qtq(const double* __restrict__ Q, const double* __restrict__ T,
                      double* __restrict__ A2sk, double* __restrict__ dg64) {
  int j = blockIdx.x * 16 + threadIdx.x, i = blockIdx.y * 16 + threadIdx.y;
  if (i >= CH || j >= CH || j < i) return;
  double acc = 0;
  for (int k = 0; k < CH; ++k) acc += Q[(size_t)k * CH + i] * T[k * CH + j];
  if (j == i) dg64[i] = acc;
  else A2sk[sk(i, j)] = acc;
}

// ---------------- stage D: fp64 polish Jacobi (exactly 1 sweep) -----------
__global__ __launch_bounds__(1024) void k_jac64(const double* __restrict__ A2sk,
                                                const double* __restrict__ dg0,
                                                double* __restrict__ eig,
                                                double2* __restrict__ rlogB) {
  extern __shared__ double As64[];
  __shared__ double2 csn[96];
  __shared__ double dg[CH];
  int t = threadIdx.x;

  int jS[5], kS[5]; int ntask = 0;
  for (int id = t; id < 4560; id += 1024) {
    int j = 0, off = 0;
    while (off + (95 - j) <= id) { off += 95 - j; ++j; }
    jS[ntask] = j; kS[ntask] = j + 1 + (id - off);
    ++ntask;
  }
  int a00[5], a01[5], a10[5], a11[5], limA[5], limB[5];
  #pragma unroll
  for (int ii = 0; ii < 5; ++ii) {
    if (ii < ntask) {
      int j = jS[ii], k = kS[ii];
      int A = j + k;
      int B = k - j;
      int dfB = (A > 95) ? (CH - A) : A;
      int bA = B * 194;
      int bB = dfB * 194;
      a00[ii] = (bA + A) * 8;
      a11[ii] = (bA + CH - A) * 8;
      a01[ii] = (bB + CH - B) * 8;
      a10[ii] = (bB + B) * 8;
      limA[ii] = (bA + CH) * 8;
      limB[ii] = (bB + CH) * 8;
    } else {
      a00[ii] = a01[ii] = a10[ii] = a11[ii] = 0;
      limA[ii] = limB[ii] = 1 << 30; jS[ii] = 0; kS[ii] = 1;
    }
  }

  for (int e = t; e < NSKEW; e += 1024) As64[e] = A2sk[e];
  if (t < CH) dg[t] = dg0[t];
  __syncthreads();

  const char* Asb = (const char*)As64;
  for (int r = 0; r < CH; ++r) {
    double m0[5], m1[5], m2[5], m3[5];
    #pragma unroll
    for (int ii = 0; ii < 5; ++ii) {
      if (ii < ntask) {
        m0[ii] = *(const double*)(Asb + a00[ii]);
        m1[ii] = *(const double*)(Asb + a01[ii]);
        if (jS[ii] != 0) {
          m2[ii] = *(const double*)(Asb + a10[ii]);
          m3[ii] = *(const double*)(Asb + a11[ii]);
        }
      }
    }
    if (t >= 1 && t < 96) {
      int p = r + t; if (p >= CH) p -= CH;
      int q = r - t; if (q < 0) q += CH;
      int ipq = sk(p, q);
      double app = dg[p], aqq = dg[q], apq = As64[ipq];
      double c = 1.0, s = 0.0, piv = apq, dp = app, dq = aqq;
      if (fabs(apq) > 4e-16 * (fabs(app) + fabs(aqq)) + 1e-300) {
        double tau = (aqq - app) / (2.0 * apq);
        double tt = copysign(1.0, tau) / (fabs(tau) + sqrt(1.0 + tau * tau));
        c = 1.0 / sqrt(1.0 + tt * tt); s = tt * c;
        dp = app - tt * apq; dq = aqq + tt * apq; piv = 0.0;
      }
      dg[p] = dp; dg[q] = dq;
      As64[ipq] = piv;
      csn[t] = make_double2(c, s);
      rlogB[(size_t)r * 95 + (t - 1)] = make_double2(c, s);
    }
    BAR_LGKM();
    #pragma unroll
    for (int ii = 0; ii < 5; ++ii) {
      if (ii < ntask) {
        double2 ck2 = csn[kS[ii]];
        if (jS[ii] == 0) {
          double vp = m0[ii], vq = m1[ii];
          *(double*)((char*)As64 + a00[ii]) = ck2.x * vp - ck2.y * vq;
          *(double*)((char*)As64 + a01[ii]) = ck2.y * vp + ck2.x * vq;
        } else {
          double2 cj2 = csn[jS[ii]];
          double n00 = ck2.x * m0[ii] - ck2.y * m1[ii];
          double n01 = ck2.y * m0[ii] + ck2.x * m1[ii];
          double n10 = ck2.x * m2[ii] - ck2.y * m3[ii];
          double n11 = ck2.y * m2[ii] + ck2.x * m3[ii];
          *(double*)((char*)As64 + a00[ii]) = cj2.x * n00 - cj2.y * n10;
          *(double*)((char*)As64 + a10[ii]) = cj2.y * n00 + cj2.x * n10;
          *(double*)((char*)As64 + a01[ii]) = cj2.x * n01 - cj2.y * n11;
          *(double*)((char*)As64 + a11[ii]) = cj2.y * n01 + cj2.x * n11;
        }
        a00[ii] += 16; if (a00[ii] >= limA[ii]) a00[ii] -= 1528;
        a11[ii] += 16; if (a11[ii] >= limA[ii]) a11[ii] -= 1528;
        a01[ii] += 16; if (a01[ii] >= limB[ii]) a01[ii] -= 1528;
        a10[ii] += 16; if (a10[ii] >= limB[ii]) a10[ii] -= 1528;
      }
    }
    BAR_LGKM();
  }
  for (int i = t; i < CH; i += 1024) eig[i] = dg[i];
}

// ---------------- apply stage-D rotations to Q rows -> V ------------------
__global__ __launch_bounds__(128) void k_replayB(const double2* __restrict__ rlogB,
                                                 const double* __restrict__ Q,
                                                 double* __restrict__ V) {
  __shared__ double vr[CH];
  int row = blockIdx.x, t = threadIdx.x;
  const int NR = CH;
  for (int j = t; j < CH; j += 128) vr[j] = Q[(size_t)row * CH + j];
  double2 nxt = (t < 95) ? rlogB[t] : make_double2(1.0, 0.0);
  BAR_LGKM();
  for (int g = 0; g < NR; ++g) {
    double2 cur = nxt;
    if (t < 95 && g + 1 < NR) nxt = rlogB[(size_t)(g + 1) * 95 + t];
    if (t < 95 && cur.y != 0.0) {
      int k = t + 1;
      int p = g + k; if (p >= CH) p -= CH;
      int q = g - k; if (q < 0) q += CH;
      double vp = vr[p], vq = vr[q];
      vr[p] = cur.x * vp - cur.y * vq;
      vr[q] = cur.y * vp + cur.x * vq;
    }
    BAR_LGKM();
  }
  for (int j = t; j < CH; j += 128) V[(size_t)row * CH + j] = vr[j];
}

// ---------------- sort eigenpairs (desc) + whitened eigvec matrix ---------
__global__ __launch_bounds__(256) void k_sortprep(const double* __restrict__ eig,
                                                  const double* __restrict__ V,
                                                  const double* __restrict__ invs,
                                                  int* __restrict__ perm,
                                                  float* __restrict__ Vw) {
  __shared__ double ev[CH];
  __shared__ int pm[CH];
  int t = threadIdx.x;
  if (t < CH) ev[t] = eig[t];
  __syncthreads();
  if (t < CH) {
    double my = ev[t];
    int rk = 0;
    for (int j = 0; j < CH; ++j) {
      double o = ev[j];
      rk += (o > my || (o == my && j < t)) ? 1 : 0;
    }
    pm[rk] = t;
  }
  __syncthreads();
  if (t < CH) perm[t] = pm[t];
  for (int e = t; e < 192 * 192; e += 256) {
    int k = e / 192, i = e - k * 192;
    float v = 0.f;
    if (k < CH && i < CH) v = (float)(invs[k] * V[(size_t)k * CH + pm[i]]);
    Vw[e] = v;
  }
}

// ---------------- pcT = (Y V)^T : [CH][NPIX], 64x64 i-tile (3x re-read) ----
// R12-verified win isolated by the R12/R13 triangle: -84us vs 32-wide tile.
__global__ __launch_bounds__(256) void k_pc(const float* __restrict__ x,
                                            const float* __restrict__ Vw,
                                            float* __restrict__ pcT) {
  __shared__ float xs[16][65];
  __shared__ float vs[16][65];
  int n0 = blockIdx.x * 64, i0 = blockIdx.y * 64;
  int t = threadIdx.x;
  int tn = t & 15, ti = t >> 4;
  float acc[4][4] = {};
  for (int k0 = 0; k0 < 192; k0 += 16) {
    {
      int col = t & 15, row = t >> 4;
      #pragma unroll
      for (int rr = 0; rr < 4; ++rr) {
        int nn = row + rr * 16;
        int k = k0 + col;
        xs[col][nn] = (k < CH) ? x[(size_t)(n0 + nn) * CH + k] : 0.f;
      }
    }
    {
      int ii = t & 63, kk = t >> 6;
      #pragma unroll
      for (int rr = 0; rr < 4; ++rr)
        vs[kk + rr * 4][ii] = Vw[(k0 + kk + rr * 4) * 192 + i0 + ii];
    }
    __syncthreads();
    #pragma unroll
    for (int kk = 0; kk < 16; ++kk) {
      float b0 = vs[kk][ti], b1 = vs[kk][ti + 16];
      float b2 = vs[kk][ti + 32], b3 = vs[kk][ti + 48];
      #pragma unroll
      for (int rr = 0; rr < 4; ++rr) {
        float a = xs[kk][tn + rr * 16];
        acc[rr][0] += a * b0;
        acc[rr][1] += a * b1;
        acc[rr][2] += a * b2;
        acc[rr][3] += a * b3;
      }
    }
    __syncthreads();
  }
  #pragma unroll
  for (int rr = 0; rr < 4; ++rr)
    #pragma unroll
    for (int bb = 0; bb < 4; ++bb) {
      int i = i0 + ti + bb * 16, n = n0 + tn + rr * 16;
      if (i < CH) pcT[(size_t)i * NPIX + n] = acc[rr][bb];
    }
}

// ---------------- DWT row pass (level 1 only) ----------------
__global__ __launch_bounds__(256) void k_row(const float* __restrict__ in,
                                             float* __restrict__ rb,
                                             int h, int w, int wd, int chS) {
  __shared__ float rowv[256];
  int bid = blockIdx.x;
  int c = bid / h, y = bid % h;
  const float* src = in + (size_t)c * chS + (size_t)y * w;
  int t = threadIdx.x;
  if (t < w) rowv[t] = src[t];
  __syncthreads();
  float* dst = rb + (size_t)(c * h + y) * (2 * wd);
  for (int o = t; o < 2 * wd; o += 256) {
    int b = (o >= wd) ? 1 : 0;
    int xp = b ? o - wd : o;
    float acc = 0.f;
    #pragma unroll
    for (int s = 0; s < 10; ++s) {
      int m = 2 * xp + 1 - s;
      if (m < 0) m = -1 - m;
      else if (m >= w) m = 2 * w - 1 - m;
      acc += (b ? g_dhi[s] : g_dlo[s]) * rowv[m];
    }
    dst[o] = acc;
  }
}

// ---------------- DWT column pass (level 1 only) -----------
__global__ __launch_bounds__(256) void k_col(const float* __restrict__ rb,
                                             float* __restrict__ llout,
                                             float* __restrict__ coeff,
                                             int h, int wd, int hd, int chSout,
                                             int offHi, int offLL, int lastlvl) {
  int c = blockIdx.z, yp = blockIdx.y;
  int xq = blockIdx.x * 256 + threadIdx.x;
  if (xq >= 2 * wd) return;
  const float* base = rb + (size_t)c * h * 2 * wd + xq;
  float lo = 0.f, hi = 0.f;
  #pragma unroll
  for (int s = 0; s < 10; ++s) {
    int m = 2 * yp + 1 - s;
    if (m < 0) m = -1 - m;
    else if (m >= h) m = 2 * h - 1 - m;
    float v = base[(size_t)m * 2 * wd];
    lo += g_dlo[s] * v;
    hi += g_dhi[s] * v;
  }
  float* cc = coeff + (size_t)c * CSTRIDE;
  if (xq < wd) {
    llout[(size_t)c * chSout + (size_t)yp * wd + xq] = lo;
    if (lastlvl) cc[offLL + yp * wd + xq] = lo;
    cc[offHi + 0 * hd * wd + yp * wd + xq] = hi;
  } else {
    int xp = xq - wd;
    cc[offHi + 1 * hd * wd + yp * wd + xp] = lo;
    cc[offHi + 2 * hd * wd + yp * wd + xp] = hi;
  }
}

// ---------------- DWT levels 2-5 fused: LDS-resident cascade --------------
#define DWT_SMEM ((17424 + 18480) * 4)
__global__ __launch_bounds__(256) void k_dwt_tail(const float* __restrict__ llin,
                                                  float* __restrict__ coeff) {
  extern __shared__ float smem[];
  float* A = smem;
  float* B = smem + 17424;
  const int hsz[5]   = {132, 70, 39, 24, 16};
  const int offHiC[4] = {52272, 66972, 71535, 73263};
  int c = blockIdx.x, t = threadIdx.x;
  float* cc = coeff + (size_t)c * CSTRIDE;
  for (int e = t; e < 132 * 132; e += 256) A[e] = llin[(size_t)c * 17424 + e];
  BAR_LGKM();
  #pragma unroll
  for (int l = 0; l < 4; ++l) {
    const int h = hsz[l], w = hsz[l], wd = hsz[l + 1], hd = hsz[l + 1];
    const int w2 = 2 * wd;
    for (int e = t; e < h * w2; e += 256) {
      int y = e / w2, o = e - y * w2;
      int b = (o >= wd) ? 1 : 0;
      int xp = b ? o - wd : o;
      float acc = 0.f;
      #pragma unroll
      for (int s = 0; s < 10; ++s) {
        int m = 2 * xp + 1 - s;
        if (m < 0) m = -1 - m;
        else if (m >= w) m = 2 * w - 1 - m;
        acc += (b ? g_dhi[s] : g_dlo[s]) * A[y * w + m];
      }
      B[y * w2 + o] = acc;
    }
    BAR_LGKM();
    for (int e = t; e < hd * w2; e += 256) {
      int yp = e / w2, xq = e - yp * w2;
      float lo = 0.f, hi = 0.f;
      #pragma unroll
      for (int s = 0; s < 10; ++s) {
        int m = 2 * yp + 1 - s;
        if (m < 0) m = -1 - m;
        else if (m >= h) m = 2 * h - 1 - m;
        float v = B[m * w2 + xq];
        lo += g_dlo[s] * v;
        hi += g_dhi[s] * v;
      }
      if (xq < wd) {
        A[yp * wd + xq] = lo;
        if (l == 3) cc[74031 + yp * wd + xq] = lo;
        cc[offHiC[l] + 0 * hd * wd + yp * wd + xq] = hi;
      } else {
        int xp = xq - wd;
        cc[offHiC[l] + 1 * hd * wd + yp * wd + xp] = lo;
        cc[offHiC[l] + 2 * hd * wd + yp * wd + xp] = hi;
      }
    }
    BAR_LGKM();
  }
}

// ---------------- SURE statistics (per-thread accumulate, then reduce) ----
__global__ __launch_bounds__(256) void k_stats(const float* __restrict__ coeff,
                                               double* __restrict__ stats, TArgs ta) {
  int c = blockIdx.y;
  const float* cc = coeff + (size_t)c * CSTRIDE;
  double sm[15], cnt[15], nrm = 0;
  #pragma unroll
  for (int q = 0; q < 15; ++q) { sm[q] = 0; cnt[q] = 0; }
  for (int idx = blockIdx.x * 256 + threadIdx.x; idx < MCOEF; idx += 24 * 256) {
    double v = (double)cc[idx];
    double v2 = v * v;
    nrm += v2;
    #pragma unroll
    for (int q = 0; q < 15; ++q) {
      sm[q] += fmin(v2, ta.t2[q]);
      cnt[q] += (v2 >= ta.t2[q]) ? 1.0 : 0.0;
    }
  }
  __shared__ double wred[4][31];
  int lane = threadIdx.x & 63, wv = threadIdx.x >> 6;
  for (int q = 0; q < 31; ++q) {
    double val = (q < 15) ? sm[q] : ((q < 30) ? cnt[q - 15] : nrm);
    #pragma unroll
    for (int o = 32; o > 0; o >>= 1) val += __shfl_down(val, o);
    if (lane == 0) wred[wv][q] = val;
  }
  __syncthreads();
  if (threadIdx.x < 31) {
    double sum = wred[0][threadIdx.x] + wred[1][threadIdx.x] +
                 wred[2][threadIdx.x] + wred[3][threadIdx.x];
    atomicAdd(&stats[c * 31 + threadIdx.x], sum);
  }
}

// ---------------- SURE scan + rank + masked projection matrix -------------
__global__ __launch_bounds__(256) void k_sure(const double* __restrict__ stats,
                                              const double* __restrict__ sqrtom,
                                              const double* __restrict__ V,
                                              const int* __restrict__ perm,
                                              const int* __restrict__ min_iter_p,
                                              float* __restrict__ Wm,
                                              int* __restrict__ meta) {
  __shared__ double st[CH * 31];
  __shared__ double minsure[CH];
  __shared__ int rankS;
  int t = threadIdx.x;
  for (int e = t; e < CH * 31; e += 256) st[e] = stats[e];
  __syncthreads();
  if (t == 0) {
    double norm2 = 0;
    for (int c = 0; c < CH; ++c) norm2 += st[c * 31 + 30];
    double K = norm2 - (double)MCOEF * (double)CH;
    double cum[15];
    for (int q = 0; q < 15; ++q) cum[q] = 0;
    for (int r = 0; r < CH; ++r) {
      double mn = 1e300;
      for (int q = 0; q < 15; ++q) {
        double sure = st[r * 31 + q] + 2.0 * st[r * 31 + 15 + q] - (double)MCOEF;
        double s = cum[q] + sure + K;
        cum[q] += s;
        if (s < mn) mn = s;
      }
      minsure[r] = mn;
    }
    int mi = *min_iter_p;
    int rank = CH - 1;
    for (int r = 0; r < CH; ++r) {
      double prev = (r == 0) ? minsure[0] : minsure[r - 1];
      bool cond = (r > mi) && !(minsure[r] > 2.0 * prev);
      if (cond) { rank = r; break; }
    }
    rankS = rank;
    meta[1] = rank;
  }
  __syncthreads();
  int rank = rankS;
  for (int e = t; e < 192 * 192; e += 256) {
    int k = e / 192, c = e - k * 192;
    float v = 0.f;
    if (k < rank && c < CH) v = (float)(sqrtom[c] * V[(size_t)c * CH + perm[k]]);
    Wm[e] = v;
  }
}

// ---------------- out = pcT^T * Wm, 64x64 c-tile (3x re-read) ----------------
// R12-verified win isolated by the R12/R13 triangle.
__global__ __launch_bounds__(256) void k_out(const float* __restrict__ pcT,
                                             const float* __restrict__ Wm,
                                             float* __restrict__ out) {
  __shared__ float psx[16][65];
  __shared__ float wsx[16][65];
  int n0 = blockIdx.x * 64, c0 = blockIdx.y * 64;
  int t = threadIdx.x;
  int tc = t & 15, tn = t >> 4;
  float acc[4][4] = {};
  for (int k0 = 0; k0 < 192; k0 += 16) {
    {
      int nn = t & 63, kk0 = t >> 6;
      #pragma unroll
      for (int rr = 0; rr < 4; ++rr) {
        int kk = kk0 + rr * 4;
        int k = k0 + kk;
        psx[kk][nn] = (k < CH) ? pcT[(size_t)k * NPIX + n0 + nn] : 0.f;
      }
    }
    {
      int cc = t & 63, kk = t >> 6;
      #pragma unroll
      for (int rr = 0; rr < 4; ++rr)
        wsx[kk + rr * 4][cc] = Wm[(k0 + kk + rr * 4) * 192 + c0 + cc];
    }
    __syncthreads();
    #pragma unroll
    for (int kk = 0; kk < 16; ++kk) {
      float b0 = wsx[kk][tc], b1 = wsx[kk][tc + 16];
      float b2 = wsx[kk][tc + 32], b3 = wsx[kk][tc + 48];
      #pragma unroll
      for (int rr = 0; rr < 4; ++rr) {
        float a = psx[kk][tn + rr * 16];
        acc[rr][0] += a * b0;
        acc[rr][1] += a * b1;
        acc[rr][2] += a * b2;
        acc[rr][3] += a * b3;
      }
    }
    __syncthreads();
  }
  #pragma unroll
  for (int rr = 0; rr < 4; ++rr)
    #pragma unroll
    for (int bb = 0; bb < 4; ++bb) {
      int n = n0 + tn + rr * 16, c = c0 + tc + bb * 16;
      if (c < CH) out[(size_t)n * CH + c] = acc[rr][bb];
    }
}

// ---------------- host ----------------
extern "C" void kernel_launch(void* const* d_in, const int* in_sizes, int n_in,
                              void* d_out, int out_size, void* d_ws, size_t ws_size,
                              hipStream_t stream) {
  const float* x = (const float*)d_in[0];
  const int* p_min_iter = (const int*)d_in[1];
  float* out = (float*)d_out;
  char* ws = (char*)d_ws;

  size_t cur = 0;
  auto A = [&](size_t b) { size_t o = cur; cur += (b + 511) & ~(size_t)511; return o; };
  double* ddp     = (double*)(ws + A((size_t)CH * CH * 8));
  double* ddpi64  = (double*)(ws + A((size_t)CH * CH * 8));
  double* Tm      = (double*)(ws + A((size_t)CH * CH * 8));
  double* V       = (double*)(ws + A((size_t)CH * CH * 8));
  double* G64     = (double*)(ws + A((size_t)CH * CH * 8));
  double* T64     = (double*)(ws + A((size_t)CH * CH * 8));
  double* Q       = (double*)(ws + A((size_t)CH * CH * 8));
  double* A2sk    = (double*)(ws + A((size_t)NSKEW * 8));
  double* dg64    = (double*)(ws + A((size_t)CH * 8));
  double* eig     = (double*)(ws + A((size_t)CH * 8));
  double* rsum    = (double*)(ws + A((size_t)CH * 8));
  double* sqrtom  = (double*)(ws + A((size_t)CH * 8));
  double* invs    = (double*)(ws + A((size_t)CH * 8));
  double* stats   = (double*)(ws + A((size_t)CH * 31 * 8));
  int* perm       = (int*)(ws + A((size_t)CH * 4));
  int* meta       = (int*)(ws + A(64));
  float* ddpi32   = (float*)(ws + A((size_t)CH * CH * 4));
  float* Gsk      = (float*)(ws + A((size_t)NSKEW * 4));
  float* dgf      = (float*)(ws + A((size_t)CH * 4));
  float* Vw       = (float*)(ws + A((size_t)192 * 192 * 4));
  float* Wm       = (float*)(ws + A((size_t)192 * 192 * 4));
  float2* rlogA   = (float2*)(ws + A((size_t)SW32 * CH * 95 * 8));
  double2* rlogB  = (double2*)(ws + A((size_t)CH * 95 * 16));
  float* pcT      = (float*)(ws + A((size_t)CH * NPIX * 4));
  float* rowbuf   = (float*)(ws + A((size_t)CH * 256 * 264 * 4));
  float* llA      = (float*)(ws + A((size_t)CH * 17424 * 4));
  float* coeff    = (float*)(ws + A((size_t)CH * CSTRIDE * 4));
  (void)ws_size; (void)in_sizes; (void)n_in; (void)out_size;

  hipMemsetAsync(ddp, 0, (size_t)CH * CH * 8, stream);
  hipMemsetAsync(rsum, 0, (size_t)CH * 8, stream);
  hipMemsetAsync(stats, 0, (size_t)CH * 31 * 8, stream);

  const int J32_SMEM = NSKEW * 4;                               // 74496
  const int J64_SMEM = NSKEW * 8;                               // 148992

  k_ddp<<<dim3(6, 6, 16), 256, 0, stream>>>(x, ddp);
  k_mirror<<<143, 256, 0, stream>>>(ddp);
  k_rsum<<<256, 256, 0, stream>>>(x, rsum);
  k_gj<<<1, 768, 0, stream>>>(ddp, ddpi32);
  k_newton1<<<dim3(12, 12), dim3(16, 16), 0, stream>>>(ddp, ddpi32, Tm);
  k_newton2<<<dim3(12, 12), dim3(16, 16), 0, stream>>>(ddpi32, Tm, ddpi64);
  k_beta<<<CH, 256, 0, stream>>>(ddp, ddpi64, rsum, sqrtom, invs);
  k_packG<<<143, 256, 0, stream>>>(ddp, invs, Gsk, dgf, G64);
  (void)hipFuncSetAttribute((const void*)k_jac32,
        hipFuncAttributeMaxDynamicSharedMemorySize, J32_SMEM);
  k_jac32<<<1, 1024, J32_SMEM, stream>>>(Gsk, dgf, rlogA);
  k_replayA<<<CH, 128, 0, stream>>>(rlogA, Q);
  k_gq<<<dim3(12, 12), dim3(16, 16), 0, stream>>>(G64, Q, T64);
  k_qtq<<<dim3(12, 12), dim3(16, 16), 0, stream>>>(Q, T64, A2sk, dg64);
  (void)hipFuncSetAttribute((const void*)k_jac64,
        hipFuncAttributeMaxDynamicSharedMemorySize, J64_SMEM);
  k_jac64<<<1, 1024, J64_SMEM, stream>>>(A2sk, dg64, eig, rlogB);
  k_replayB<<<CH, 128, 0, stream>>>(rlogB, Q, V);
  k_sortprep<<<1, 256, 0, stream>>>(eig, V, invs, perm, Vw);
  k_pc<<<dim3(1024, 3), 256, 0, stream>>>(x, Vw, pcT);

  // DWT level 1 (256 -> 132) via row/col, then levels 2-5 fused in LDS
  k_row<<<CH * 256, 256, 0, stream>>>(pcT, rowbuf, 256, 256, 132, NPIX);
  k_col<<<dim3(2, 132, CH), 256, 0, stream>>>(
      rowbuf, llA, coeff, 256, 132, 132, 132 * 132, 0, 74031, 0);
  (void)hipFuncSetAttribute((const void*)k_dwt_tail,
        hipFuncAttributeMaxDynamicSharedMemorySize, DWT_SMEM);
  k_dwt_tail<<<CH, 256, DWT_SMEM, stream>>>(llA, coeff);

  TArgs ta;
  {
    double tmax = sqrt(log((double)MCOEF));
    for (int j = 0; j < 15; ++j) { double tv = tmax * j / 14.0; ta.t2[j] = tv * tv; }
  }
  k_stats<<<dim3(24, CH), 256, 0, stream>>>(coeff, stats, ta);
  k_sure<<<1, 256, 0, stream>>>(stats, sqrtom, V, perm, p_min_iter, Wm, meta);
  k_out<<<dim3(1024, 3), 256, 0, stream>>>(pcT, Wm, out);
}